// Round 12
// baseline (405.920 us; speedup 1.0000x reference)
//
#include <hip/hip_runtime.h>
#include <hip/hip_bf16.h>
#include <math.h>

// ---------------- constants ----------------
#define TB 8
#define TT 64000
#define NFRAMES 251
#define NROWS (TB*NFRAMES)      // 2008
#define MPAD 2048
#define NBINS 513
#define NBPAD 576
#define NNODE 250
#define NODE_DIM 4116
#define KPAD 4128

typedef __attribute__((ext_vector_type(8))) short short8;
typedef __attribute__((ext_vector_type(4))) float floatx4;

static __device__ __forceinline__ unsigned short f2bf(float x) {
    __hip_bfloat16 h = __float2bfloat16(x);
    return *(unsigned short*)&h;
}
static __device__ __forceinline__ float bf2f(unsigned short u) {
    __hip_bfloat16 h = *(__hip_bfloat16*)&u;
    return __bfloat162float(h);
}

// ---------------- small prep kernels ----------------

__global__ void k_fold(const float* __restrict__ c1w, const float* __restrict__ c1b,
                       const float* __restrict__ g1bn, const float* __restrict__ b1bn,
                       const float* __restrict__ c2w, const float* __restrict__ c2b,
                       const float* __restrict__ g2bn, const float* __restrict__ b2bn,
                       float* __restrict__ w1f, float* __restrict__ b1f,
                       float* __restrict__ w2f, float* __restrict__ b2f) {
    int idx = blockIdx.x * 256 + threadIdx.x;
    float inv = rsqrtf(1.0f + 1e-5f);
    if (idx < 9216) {
        int co = idx / 288;
        w2f[idx] = c2w[idx] * (g2bn[co] * inv);
    } else if (idx < 9216 + 288) {
        int r = idx - 9216;
        w1f[r] = c1w[r] * (g1bn[r / 9] * inv);
    } else if (idx < 9216 + 288 + 32) {
        int c = idx - 9504;
        b1f[c] = c1b[c] * (g1bn[c] * inv) + b1bn[c];
    } else if (idx < 9216 + 288 + 64) {
        int c = idx - 9536;
        b2f[c] = c2b[c] * (g2bn[c] * inv) + b2bn[c];
    }
}

// pack conv2 weights into MFMA B-fragment order, bf16.
__global__ void k_pack(const float* __restrict__ w2f, unsigned short* __restrict__ Bp) {
    int idx = blockIdx.x * 256 + threadIdx.x;
    if (idx >= 9216) return;
    int j = idx & 7, lane = (idx >> 3) & 63, ct = (idx >> 9) & 1, s = idx >> 10;
    int co = ct * 16 + (lane & 15);
    int ci = (lane >> 4) * 8 + j;
    Bp[idx] = f2bf(w2f[co * 288 + ci * 9 + s]);
}

// transpose gat1_W -> Wt [512][KPAD] bf16 with K-permutation:
// dest k' = 20 + f*16 + c  <->  source k = 20 + c*256 + f  (c<16, f<256); k<20 identity
__global__ __launch_bounds__(256) void k_wt(const float* __restrict__ W,
                                            unsigned short* __restrict__ Wt) {
    __shared__ unsigned short tile[64][65];
    int kt = blockIdx.x, nt = blockIdx.y;
    int tid = threadIdx.x;
    for (int idx = tid; idx < 4096; idx += 256) {
        int r = idx >> 6, c = idx & 63;
        int kp = kt * 64 + r;
        int k;
        if (kp < 20) k = kp;
        else if (kp < NODE_DIM) { int t = kp - 20; k = 20 + (t & 15) * 256 + (t >> 4); }
        else k = -1;
        float v = (k >= 0) ? W[k * 512 + nt * 64 + c] : 0.f;
        tile[r][c] = f2bf(v);
    }
    __syncthreads();
    for (int idx = tid; idx < 4096; idx += 256) {
        int nl = idx >> 6, kl = idx & 63;
        int k = kt * 64 + kl;
        if (k < KPAD)
            Wt[(size_t)(nt * 64 + nl) * KPAD + k] = tile[kl][nl];
    }
}

// sinc weights: 4-tap prefix-summed, transposed, padded bf16: wbt[32][1056]
__global__ void k_wbt(const float* __restrict__ sw, unsigned short* __restrict__ wbt) {
    int idx = blockIdx.x * 256 + threadIdx.x;
    if (idx >= 32 * 1056) return;
    int c = idx / 1056, m = idx - c * 1056;
    float s = 0.f;
    if (c < 20 && m < 1027) {
        #pragma unroll
        for (int d = 0; d < 4; d++) {
            int k = m - d;
            if (k >= 0 && k < 1024) s += sw[c * 1024 + k];
        }
        s *= 0.25f;
    }
    wbt[idx] = f2bf(s);
}

// DFT basis, bf16 hi/lo split; rows [NBINS..NBPAD) zero
__global__ void k_basis_bf(unsigned short* __restrict__ ch, unsigned short* __restrict__ cl,
                           unsigned short* __restrict__ sh, unsigned short* __restrict__ sl) {
    int idx = blockIdx.x * 256 + threadIdx.x;
    if (idx >= NBPAD * 1024) return;
    int k = idx >> 10, n = idx & 1023;
    float s = 0.f, c = 0.f;
    if (k < NBINS) {
        int mm = (k * n) & 1023;
        sincospif((float)mm * (1.0f / 512.0f), &s, &c);
    }
    unsigned short chv = f2bf(c), shv = f2bf(s);
    ch[idx] = chv; cl[idx] = f2bf(c - bf2f(chv));
    sh[idx] = shv; sl[idx] = f2bf(s - bf2f(shv));
}

// frames (reflect-padded) -> bf16 hi/lo, rows [NROWS..MPAD) zero
__global__ void k_frames_bf(const float* __restrict__ x,
                            unsigned short* __restrict__ fh, unsigned short* __restrict__ fl) {
    int idx = blockIdx.x * 256 + threadIdx.x;
    if (idx >= MPAD * 1024) return;
    int m = idx >> 10, n = idx & 1023;
    float v = 0.f;
    if (m < NROWS) {
        int b = m / NFRAMES, i = m - b * NFRAMES;
        int j = i * 256 + n - 512;
        if (j < 0) j = -j;
        if (j >= TT) j = 2 * TT - 2 - j;
        v = x[b * TT + j];
    }
    unsigned short h = f2bf(v);
    fh[idx] = h;
    fl[idx] = f2bf(v - bf2f(h));
}

// ---------------- sinc conv as MFMA GEMM: nodes[b][u][0..19] ----------------
__global__ __launch_bounds__(256) void k_sincm(const float* __restrict__ x,
                                               const unsigned short* __restrict__ wbt,
                                               unsigned short* __restrict__ nodesb) {
    __shared__ __align__(16) unsigned short xs[2080];
    int b = blockIdx.x;
    int tid = threadIdx.x;
    for (int i = tid; i < 2080; i += 256) {
        int g = i - 512;
        float v = (g >= 0 && g < TT) ? x[b * TT + g] : 0.f;
        xs[i] = f2bf(v);
    }
    __syncthreads();
    int w = tid >> 6, lane = tid & 63;
    int q = lane >> 4, col = lane & 15;
    floatx4 acc[4][2];
    #pragma unroll
    for (int mi = 0; mi < 4; mi++)
        #pragma unroll
        for (int ni = 0; ni < 2; ni++)
            acc[mi][ni] = (floatx4){0.f, 0.f, 0.f, 0.f};
    for (int K0 = 0; K0 < 1056; K0 += 32) {
        short8 af[4];
        #pragma unroll
        for (int mi = 0; mi < 4; mi++) {
            int u = w * 64 + mi * 16 + col;
            int off = 4 * u + K0 + q * 8;
            unsigned long long lo = *(const unsigned long long*)&xs[off];
            unsigned long long hi = *(const unsigned long long*)&xs[off + 4];
            union { unsigned long long u64[2]; short8 s8; } cv;
            cv.u64[0] = lo; cv.u64[1] = hi;
            af[mi] = cv.s8;
        }
        short8 bf[2];
        #pragma unroll
        for (int ni = 0; ni < 2; ni++) {
            int c = ni * 16 + col;
            bf[ni] = *(const short8*)(wbt + (size_t)c * 1056 + K0 + q * 8);
        }
        #pragma unroll
        for (int mi = 0; mi < 4; mi++)
            #pragma unroll
            for (int ni = 0; ni < 2; ni++)
                acc[mi][ni] = __builtin_amdgcn_mfma_f32_16x16x32_bf16(af[mi], bf[ni], acc[mi][ni], 0, 0, 0);
    }
    #pragma unroll
    for (int mi = 0; mi < 4; mi++)
        #pragma unroll
        for (int ni = 0; ni < 2; ni++)
            #pragma unroll
            for (int rr = 0; rr < 4; rr++) {
                int u = w * 64 + mi * 16 + q * 4 + rr;
                int c = ni * 16 + col;
                if (u < NNODE && c < 20)
                    nodesb[(size_t)(b * NNODE + u) * KPAD + c] = f2bf(acc[mi][ni][rr]);
            }
}

// ---------------- DFT via bf16 MFMA, split-K over blockIdx.z -> f32 partials ----------------
__global__ __launch_bounds__(256) void k_dft_mfma(const unsigned short* __restrict__ fh,
                                                  const unsigned short* __restrict__ fl,
                                                  const unsigned short* __restrict__ ch,
                                                  const unsigned short* __restrict__ cl,
                                                  const unsigned short* __restrict__ sh,
                                                  const unsigned short* __restrict__ sl,
                                                  float* __restrict__ dftR,
                                                  float* __restrict__ dftI) {
    __shared__ __align__(16) unsigned short Ah[64 * 40];
    __shared__ __align__(16) unsigned short Al[64 * 40];
    __shared__ __align__(16) unsigned short Bch[64 * 40];
    __shared__ __align__(16) unsigned short Bcl[64 * 40];
    __shared__ __align__(16) unsigned short Bsh[64 * 40];
    __shared__ __align__(16) unsigned short Bsl[64 * 40];
    int tid = threadIdx.x;
    int N0 = blockIdx.x * 64, M0 = blockIdx.y * 64;
    int kc = blockIdx.z;
    int sr = tid >> 2, sc = (tid & 3) * 8;
    size_t aoff = (size_t)(M0 + sr) * 1024 + sc;
    size_t boff = (size_t)(N0 + sr) * 1024 + sc;
    int w = tid >> 6, lane = tid & 63;
    int q = lane >> 4, col = lane & 15;
    int mb = (w >> 1) * 32, nb = (w & 1) * 32;
    floatx4 aR[2][2], aI[2][2];
    #pragma unroll
    for (int mi = 0; mi < 2; mi++)
        #pragma unroll
        for (int ni = 0; ni < 2; ni++) {
            aR[mi][ni] = (floatx4){0.f, 0.f, 0.f, 0.f};
            aI[mi][ni] = (floatx4){0.f, 0.f, 0.f, 0.f};
        }

    for (int K0 = kc * 256; K0 < kc * 256 + 256; K0 += 32) {
        *(short8*)&Ah[sr * 40 + sc]  = *(const short8*)(fh + aoff + K0);
        *(short8*)&Al[sr * 40 + sc]  = *(const short8*)(fl + aoff + K0);
        *(short8*)&Bch[sr * 40 + sc] = *(const short8*)(ch + boff + K0);
        *(short8*)&Bcl[sr * 40 + sc] = *(const short8*)(cl + boff + K0);
        *(short8*)&Bsh[sr * 40 + sc] = *(const short8*)(sh + boff + K0);
        *(short8*)&Bsl[sr * 40 + sc] = *(const short8*)(sl + boff + K0);
        __syncthreads();
        short8 ahv[2], alv[2], chv[2], clv[2], shv[2], slv[2];
        #pragma unroll
        for (int mi = 0; mi < 2; mi++) {
            ahv[mi] = *(const short8*)&Ah[(mb + mi * 16 + col) * 40 + q * 8];
            alv[mi] = *(const short8*)&Al[(mb + mi * 16 + col) * 40 + q * 8];
        }
        #pragma unroll
        for (int ni = 0; ni < 2; ni++) {
            chv[ni] = *(const short8*)&Bch[(nb + ni * 16 + col) * 40 + q * 8];
            clv[ni] = *(const short8*)&Bcl[(nb + ni * 16 + col) * 40 + q * 8];
            shv[ni] = *(const short8*)&Bsh[(nb + ni * 16 + col) * 40 + q * 8];
            slv[ni] = *(const short8*)&Bsl[(nb + ni * 16 + col) * 40 + q * 8];
        }
        #pragma unroll
        for (int mi = 0; mi < 2; mi++)
            #pragma unroll
            for (int ni = 0; ni < 2; ni++) {
                aR[mi][ni] = __builtin_amdgcn_mfma_f32_16x16x32_bf16(ahv[mi], chv[ni], aR[mi][ni], 0, 0, 0);
                aR[mi][ni] = __builtin_amdgcn_mfma_f32_16x16x32_bf16(ahv[mi], clv[ni], aR[mi][ni], 0, 0, 0);
                aR[mi][ni] = __builtin_amdgcn_mfma_f32_16x16x32_bf16(alv[mi], chv[ni], aR[mi][ni], 0, 0, 0);
                aI[mi][ni] = __builtin_amdgcn_mfma_f32_16x16x32_bf16(ahv[mi], shv[ni], aI[mi][ni], 0, 0, 0);
                aI[mi][ni] = __builtin_amdgcn_mfma_f32_16x16x32_bf16(ahv[mi], slv[ni], aI[mi][ni], 0, 0, 0);
                aI[mi][ni] = __builtin_amdgcn_mfma_f32_16x16x32_bf16(alv[mi], shv[ni], aI[mi][ni], 0, 0, 0);
            }
        __syncthreads();
    }
    float* outR = dftR + (size_t)kc * MPAD * NBPAD;
    float* outI = dftI + (size_t)kc * MPAD * NBPAD;
    #pragma unroll
    for (int mi = 0; mi < 2; mi++)
        #pragma unroll
        for (int ni = 0; ni < 2; ni++)
            #pragma unroll
            for (int rr = 0; rr < 4; rr++) {
                int m = M0 + mb + mi * 16 + q * 4 + rr;
                int bin = N0 + nb + ni * 16 + col;
                outR[(size_t)m * NBPAD + bin] = aR[mi][ni][rr];
                outI[(size_t)m * NBPAD + bin] = aI[mi][ni][rr];
            }
}

// reduce 4 Re/Im partials -> S0[b][bin][i] = log(|.|+1e-9)
__global__ __launch_bounds__(256) void k_dftred(const float* __restrict__ dftR,
                                                const float* __restrict__ dftI,
                                                float* __restrict__ S0) {
    int idx = blockIdx.x * 256 + threadIdx.x;
    if (idx >= NROWS * NBINS) return;
    int m = idx / NBINS, bin = idx - m * NBINS;
    size_t o = (size_t)m * NBPAD + bin;
    const size_t st = (size_t)MPAD * NBPAD;
    float re = dftR[o] + dftR[o + st] + dftR[o + 2 * st] + dftR[o + 3 * st];
    float im = dftI[o] + dftI[o + st] + dftI[o + 2 * st] + dftI[o + 3 * st];
    int b = m / NFRAMES, i = m - b * NFRAMES;
    S0[(b * NBINS + bin) * NFRAMES + i] = logf(sqrtf(fmaf(re, re, im * im)) + 1e-9f);
}

// ---------------- conv1+BN+ReLU -> o1g[b][513][251][32] bf16 channels-last ----------------
__global__ __launch_bounds__(256) void k_conv1(const float* __restrict__ S0,
                                               const float* __restrict__ w1f,
                                               const float* __restrict__ b1f,
                                               unsigned short* __restrict__ o1g) {
    __shared__ float w1s[288];
    __shared__ float b1s[32];
    int tid = threadIdx.x;
    for (int i = tid; i < 288; i += 256) w1s[i] = w1f[i];
    if (tid < 32) b1s[tid] = b1f[tid];
    __syncthreads();
    int r = blockIdx.x;
    int b = blockIdx.y;
    int t = tid;
    if (t >= 251) return;
    float sv[9];
    #pragma unroll
    for (int di = 0; di < 3; di++) {
        int rr = r - 1 + di;
        #pragma unroll
        for (int dj = 0; dj < 3; dj++) {
            int tt = t - 1 + dj;
            float v = 0.f;
            if (rr >= 0 && rr < 513 && tt >= 0 && tt < 251)
                v = S0[(b * 513 + rr) * 251 + tt];
            sv[di * 3 + dj] = v;
        }
    }
    unsigned short ov[32];
    #pragma unroll
    for (int ci = 0; ci < 32; ci++) {
        float a = b1s[ci];
        const float* wp = &w1s[ci * 9];
        #pragma unroll
        for (int k = 0; k < 9; k++) a = fmaf(sv[k], wp[k], a);
        ov[ci] = f2bf(fmaxf(a, 0.f));
    }
    unsigned short* dst = o1g + ((size_t)(b * 513 + r) * 251 + t) * 32;
    #pragma unroll
    for (int i = 0; i < 4; i++)
        *(short8*)(dst + i * 8) = *(const short8*)&ov[i * 8];
}

// ---------------- conv2: wide LDS tile, MFMA from LDS, pool, coalesced store ----------------
__global__ __launch_bounds__(256) void k_conv2m(const unsigned short* __restrict__ o1g,
                                                const unsigned short* __restrict__ Bp,
                                                const float* __restrict__ b2f,
                                                unsigned short* __restrict__ nodesb) {
    __shared__ __align__(16) unsigned short o1s[18 * 34 * 32];  // 39.2 KB; reused as repack
    __shared__ float b2s[32];
    int tid = threadIdx.x;
    int b = blockIdx.z;
    int F0 = blockIdx.y * 8;
    int T0 = blockIdx.x * 16;
    if (tid < 32) b2s[tid] = b2f[tid];
    short8 z8 = {0, 0, 0, 0, 0, 0, 0, 0};
    const unsigned short* ob = o1g + (size_t)b * 513 * 251 * 32;

    for (int idx = tid; idx < 2448; idx += 256) {
        int r = idx / 136, rem = idx - r * 136;
        int t = rem >> 2, o = rem & 3;
        int r1 = 2 * F0 - 1 + r, t1 = 2 * T0 - 1 + t;
        short8 v = z8;
        if (r1 >= 0 && r1 < 513 && t1 >= 0 && t1 < 251)
            v = *(const short8*)(ob + ((size_t)r1 * 251 + t1) * 32 + o * 8);
        *(short8*)&o1s[(r * 34 + t) * 32 + o * 8] = v;
    }
    __syncthreads();

    int lane = tid & 63, w = tid >> 6;
    int q = lane >> 4, col = lane & 15;
    floatx4 acc[2][4][2];
    #pragma unroll
    for (int tt = 0; tt < 2; tt++)
        #pragma unroll
        for (int rt = 0; rt < 4; rt++)
            #pragma unroll
            for (int ct = 0; ct < 2; ct++)
                acc[tt][rt][ct] = (floatx4){0.f, 0.f, 0.f, 0.f};

    #pragma unroll
    for (int s = 0; s < 9; s++) {
        const int di = s / 3, dj = s % 3;
        short8 bf0 = *(const short8*)&Bp[(s * 2 + 0) * 512 + lane * 8];
        short8 bf1 = *(const short8*)&Bp[(s * 2 + 1) * 512 + lane * 8];
        #pragma unroll
        for (int tt = 0; tt < 2; tt++)
            #pragma unroll
            for (int rt = 0; rt < 4; rt++) {
                short8 af = *(const short8*)&o1s[((w * 4 + rt + di) * 34 + (col + tt * 16 + dj)) * 32 + q * 8];
                acc[tt][rt][0] = __builtin_amdgcn_mfma_f32_16x16x32_bf16(af, bf0, acc[tt][rt][0], 0, 0, 0);
                acc[tt][rt][1] = __builtin_amdgcn_mfma_f32_16x16x32_bf16(af, bf1, acc[tt][rt][1], 0, 0, 0);
            }
    }
    __syncthreads();

    unsigned short* nb = o1s;
    #pragma unroll
    for (int tt = 0; tt < 2; tt++)
        #pragma unroll
        for (int ct = 0; ct < 2; ct++) {
            float bb = b2s[ct * 16 + col];
            #pragma unroll
            for (int fp2 = 0; fp2 < 2; fp2++)
                #pragma unroll
                for (int tc2 = 0; tc2 < 2; tc2++) {
                    float m0 = fmaxf(
                        fmaxf(acc[tt][2 * fp2][ct][2 * tc2], acc[tt][2 * fp2][ct][2 * tc2 + 1]),
                        fmaxf(acc[tt][2 * fp2 + 1][ct][2 * tc2], acc[tt][2 * fp2 + 1][ct][2 * tc2 + 1]));
                    float v = fmaxf(m0 + bb, 0.f);
                    int nl = (tt * 8 + 2 * q + tc2) * 2 + ct;
                    int fl = 2 * w + fp2;
                    nb[nl * 136 + fl * 16 + col] = f2bf(v);
                }
        }
    __syncthreads();

    int nl = tid >> 3, part = tid & 7;
    int node_g = 2 * T0 + nl;
    if (node_g < NNODE) {
        unsigned short* dst = nodesb + (size_t)(b * NNODE + node_g) * KPAD + 20 + F0 * 16 + part * 16;
        *(short8*)(dst)     = *(const short8*)&nb[nl * 136 + part * 16];
        *(short8*)(dst + 8) = *(const short8*)&nb[nl * 136 + part * 16 + 8];
    }
}

// ---------------- GAT1 GEMM split-K (bf16 MFMA): hpart[kc][2000][512] ----------------
__global__ __launch_bounds__(256) void k_gat1s(const unsigned short* __restrict__ A,
                                               const unsigned short* __restrict__ Bt,
                                               float* __restrict__ hpart) {
    __shared__ __align__(16) unsigned short As[64 * 40];
    __shared__ __align__(16) unsigned short Bs[64 * 40];
    int tid = threadIdx.x;
    int N0 = blockIdx.x * 64, M0 = blockIdx.y * 64;
    int kc = blockIdx.z;
    int ks = (kc == 0) ? 0 : (33 + 32 * (kc - 1));
    int ke = 33 + 32 * kc;
    if (kc == 0) ke = 33;
    int sr = tid >> 2, sc = (tid & 3) * 8;
    int w = tid >> 6, lane = tid & 63;
    int q = lane >> 4, col = lane & 15;
    int mb = (w >> 1) * 32, nb = (w & 1) * 32;
    floatx4 acc[2][2];
    acc[0][0] = acc[0][1] = acc[1][0] = acc[1][1] = (floatx4){0.f, 0.f, 0.f, 0.f};
    short8 z8 = {0, 0, 0, 0, 0, 0, 0, 0};
    int mA = M0 + sr;
    bool mv = mA < 2000;
    const unsigned short* pa = A + (size_t)mA * KPAD + sc;
    const unsigned short* pb = Bt + (size_t)(N0 + sr) * KPAD + sc;

    for (int kk = ks; kk < ke; kk++) {
        int K0 = kk * 32;
        short8 va = mv ? *(const short8*)(pa + K0) : z8;
        short8 vb = *(const short8*)(pb + K0);
        *(short8*)&As[sr * 40 + sc] = va;
        *(short8*)&Bs[sr * 40 + sc] = vb;
        __syncthreads();
        short8 a0 = *(const short8*)&As[(mb + col) * 40 + q * 8];
        short8 a1 = *(const short8*)&As[(mb + 16 + col) * 40 + q * 8];
        short8 b0 = *(const short8*)&Bs[(nb + col) * 40 + q * 8];
        short8 b1 = *(const short8*)&Bs[(nb + 16 + col) * 40 + q * 8];
        acc[0][0] = __builtin_amdgcn_mfma_f32_16x16x32_bf16(a0, b0, acc[0][0], 0, 0, 0);
        acc[0][1] = __builtin_amdgcn_mfma_f32_16x16x32_bf16(a0, b1, acc[0][1], 0, 0, 0);
        acc[1][0] = __builtin_amdgcn_mfma_f32_16x16x32_bf16(a1, b0, acc[1][0], 0, 0, 0);
        acc[1][1] = __builtin_amdgcn_mfma_f32_16x16x32_bf16(a1, b1, acc[1][1], 0, 0, 0);
        __syncthreads();
    }
    float* out = hpart + (size_t)kc * 1024000;
    #pragma unroll
    for (int mi = 0; mi < 2; mi++)
        #pragma unroll
        for (int ni = 0; ni < 2; ni++)
            #pragma unroll
            for (int rr = 0; rr < 4; rr++) {
                int m = M0 + mb + mi * 16 + q * 4 + rr;
                if (m < 2000)
                    out[m * 512 + N0 + nb + ni * 16 + col] = acc[mi][ni][rr];
            }
}

// reduce 4 partials -> h1 f32 + h1t bf16 [bh][f][256]
__global__ __launch_bounds__(256) void k_hred(const float* __restrict__ hpart,
                                              float* __restrict__ h1,
                                              unsigned short* __restrict__ h1t) {
    int idx = blockIdx.x * 256 + threadIdx.x;
    if (idx >= 1024000) return;
    float s = hpart[idx] + hpart[idx + 1024000] + hpart[idx + 2048000] + hpart[idx + 3072000];
    h1[idx] = s;
    int m = idx >> 9, n = idx & 511;
    int bb = m / NNODE, j = m - bb * NNODE;
    int hh = n >> 6, f = n & 63;
    h1t[((size_t)((bb * 8 + hh) * 64 + f)) * 256 + j] = f2bf(s);
}

// ---------------- GAT1 scores / max ----------------
__global__ __launch_bounds__(256) void k_scores1(const float* __restrict__ h1,
                                                 const float* __restrict__ asrc,
                                                 const float* __restrict__ adst,
                                                 float* __restrict__ ssrc,
                                                 float* __restrict__ sdst) {
    int row = blockIdx.x * 4 + (threadIdx.x >> 6);
    int lane = threadIdx.x & 63;
    if (row >= 2000) return;
    for (int h = 0; h < 8; h++) {
        float v = h1[row * 512 + h * 64 + lane];
        float ps = v * asrc[h * 64 + lane];
        float pd = v * adst[h * 64 + lane];
        for (int off = 32; off > 0; off >>= 1) {
            ps += __shfl_down(ps, off);
            pd += __shfl_down(pd, off);
        }
        if (lane == 0) { ssrc[row * 8 + h] = ps; sdst[row * 8 + h] = pd; }
    }
}

__global__ __launch_bounds__(64) void k_smax1(const float* __restrict__ ssrc,
                                              float* __restrict__ smax) {
    int bh = blockIdx.x;
    int b = bh >> 3, h = bh & 7;
    int lane = threadIdx.x;
    float m = -1e30f;
    for (int n = lane; n < NNODE; n += 64) m = fmaxf(m, ssrc[(b * NNODE + n) * 8 + h]);
    for (int off = 32; off > 0; off >>= 1) m = fmaxf(m, __shfl_down(m, off));
    if (lane == 0) smax[bh] = m;
}

// ---------------- GAT1 attention weights: Pn[bh][256][256] bf16 normalized ----------------
__global__ __launch_bounds__(256) void k_attw(const float* __restrict__ ssrc,
                                              const float* __restrict__ sdst,
                                              const float* __restrict__ smax,
                                              unsigned short* __restrict__ Pn) {
    int bh = blockIdx.x;
    int b = bh >> 3, h = bh & 7;
    int tid = threadIdx.x;
    __shared__ float ss[NNODE];
    for (int j = tid; j < NNODE; j += 256) ss[j] = ssrc[(b * NNODE + j) * 8 + h];
    __syncthreads();
    unsigned short* row = Pn + ((size_t)bh * 256 + tid) * 256;
    short8 z8 = {0, 0, 0, 0, 0, 0, 0, 0};
    if (tid >= NNODE) {
        #pragma unroll
        for (int j = 0; j < 256; j += 8) *(short8*)(row + j) = z8;
        return;
    }
    float d = sdst[(b * NNODE + tid) * 8 + h];
    float e0 = d + smax[bh];
    float mx = e0 > 0.f ? e0 : 0.2f * e0;
    float den = 0.f;
    for (int j = 0; j < NNODE; j++) {
        float e = d + ss[j];
        e = e > 0.f ? e : 0.2f * e;
        den += __expf(e - mx);
    }
    float rden = 1.f / den;
    for (int j0 = 0; j0 < 256; j0 += 8) {
        unsigned short wv[8];
        #pragma unroll
        for (int jj = 0; jj < 8; jj++) {
            int j = j0 + jj;
            float wt = 0.f;
            if (j < NNODE) {
                float e = d + ss[j];
                e = e > 0.f ? e : 0.2f * e;
                wt = __expf(e - mx) * rden;
            }
            wv[jj] = f2bf(wt);
        }
        *(short8*)(row + j0) = *(const short8*)wv;
    }
}

// ---------------- GAT1 attention apply (MFMA): g1 = Pn @ h1t^T + bias, relu ----------------
__global__ __launch_bounds__(256) void k_attnv(const unsigned short* __restrict__ Pn,
                                               const unsigned short* __restrict__ h1t,
                                               const float* __restrict__ bias,
                                               float* __restrict__ g1) {
    int bh = blockIdx.x;
    int b = bh >> 3, h = bh & 7;
    int tid = threadIdx.x;
    int w = tid >> 6, lane = tid & 63;
    int q = lane >> 4, col = lane & 15;
    const unsigned short* Pb = Pn + (size_t)bh * 65536;
    const unsigned short* Hb = h1t + (size_t)bh * 16384;
    floatx4 acc[4][4];
    #pragma unroll
    for (int mi = 0; mi < 4; mi++)
        #pragma unroll
        for (int ni = 0; ni < 4; ni++)
            acc[mi][ni] = (floatx4){0.f, 0.f, 0.f, 0.f};
    for (int k0 = 0; k0 < 256; k0 += 32) {
        short8 af[4], bf[4];
        #pragma unroll
        for (int mi = 0; mi < 4; mi++)
            af[mi] = *(const short8*)(Pb + (size_t)((w * 4 + mi) * 16 + col) * 256 + k0 + q * 8);
        #pragma unroll
        for (int ni = 0; ni < 4; ni++)
            bf[ni] = *(const short8*)(Hb + (size_t)(ni * 16 + col) * 256 + k0 + q * 8);
        #pragma unroll
        for (int mi = 0; mi < 4; mi++)
            #pragma unroll
            for (int ni = 0; ni < 4; ni++)
                acc[mi][ni] = __builtin_amdgcn_mfma_f32_16x16x32_bf16(af[mi], bf[ni], acc[mi][ni], 0, 0, 0);
    }
    #pragma unroll
    for (int mi = 0; mi < 4; mi++)
        #pragma unroll
        for (int ni = 0; ni < 4; ni++)
            #pragma unroll
            for (int rr = 0; rr < 4; rr++) {
                int i = (w * 4 + mi) * 16 + q * 4 + rr;
                int f = ni * 16 + col;
                if (i < NNODE)
                    g1[(b * NNODE + i) * 512 + h * 64 + f] =
                        fmaxf(acc[mi][ni][rr] + bias[h * 64 + f], 0.f);
            }
}

// ---------------- GAT2 ----------------
__global__ __launch_bounds__(256) void k_h2(const float* __restrict__ g1,
                                            const float* __restrict__ W2,
                                            const float* __restrict__ a2src,
                                            const float* __restrict__ a2dst,
                                            float* __restrict__ h2,
                                            float* __restrict__ s2src,
                                            float* __restrict__ s2dst) {
    int row = blockIdx.x * 4 + (threadIdx.x >> 6);
    if (row >= 2000) return;
    int lane = threadIdx.x & 63;
    int o = lane & 31, half = lane >> 5;
    const float* gr = &g1[row * 512 + half * 256];
    float acc = 0.f;
    for (int k = 0; k < 256; k++) acc = fmaf(gr[k], W2[(half * 256 + k) * 32 + o], acc);
    acc += __shfl_down(acc, 32);
    float ps = acc * a2src[o], pd = acc * a2dst[o];
    for (int off = 16; off > 0; off >>= 1) {
        ps += __shfl_down(ps, off, 32);
        pd += __shfl_down(pd, off, 32);
    }
    if (lane == 0) { s2src[row] = ps; s2dst[row] = pd; }
    if (lane < 32) h2[row * 32 + o] = acc;
}

__global__ __launch_bounds__(64) void k_smax2(const float* __restrict__ s2src,
                                              float* __restrict__ smax2) {
    int b = blockIdx.x, lane = threadIdx.x;
    float m = -1e30f;
    for (int n = lane; n < NNODE; n += 64) m = fmaxf(m, s2src[b * NNODE + n]);
    for (int off = 32; off > 0; off >>= 1) m = fmaxf(m, __shfl_down(m, off));
    if (lane == 0) smax2[b] = m;
}

__global__ __launch_bounds__(256) void k_attn2(const float* __restrict__ h2,
                                               const float* __restrict__ s2src,
                                               const float* __restrict__ s2dst,
                                               const float* __restrict__ smax2,
                                               const float* __restrict__ bias2,
                                               float* __restrict__ g2) {
    int it = blockIdx.x, b = blockIdx.y;
    int tid = threadIdx.x, lane = tid & 63, wv = tid >> 6;
    __shared__ float ss[NNODE];
    for (int n = tid; n < NNODE; n += 256) ss[n] = s2src[b * NNODE + n];
    __syncthreads();
    int i = it * 4 + wv;
    if (i >= NNODE) return;
    int f = lane & 31, half = lane >> 5;
    float d = s2dst[b * NNODE + i];
    float e0 = d + smax2[b];
    float mx = e0 > 0.f ? e0 : 0.2f * e0;
    float acc = 0.f, den = 0.f;
    for (int j = half; j < NNODE; j += 2) {
        float e = d + ss[j];
        e = e > 0.f ? e : 0.2f * e;
        float w = __expf(e - mx);
        den += w;
        acc = fmaf(w, h2[(b * NNODE + j) * 32 + f], acc);
    }
    acc += __shfl_down(acc, 32);
    den += __shfl_down(den, 32);
    if (lane < 32) g2[(b * NNODE + i) * 32 + f] = acc / den + bias2[f];
}

__global__ __launch_bounds__(256) void k_emb(const float* __restrict__ g2,
                                             float* __restrict__ emb,
                                             float* __restrict__ dout) {
    int b = blockIdx.x;
    int f = threadIdx.x & 31, g = threadIdx.x >> 5;
    __shared__ float red[8][32];
    float s = 0.f;
    for (int i = g; i < NNODE; i += 8) s += g2[(b * NNODE + i) * 32 + f];
    red[g][f] = s;
    __syncthreads();
    if (threadIdx.x < 32) {
        float t = 0.f;
        #pragma unroll
        for (int gg = 0; gg < 8; gg++) t += red[gg][f];
        t *= (1.0f / 250.0f);
        emb[b * 32 + f] = t;
        dout[16 + b * 32 + f] = t;
    }
}

__global__ __launch_bounds__(256) void k_fc(const float* __restrict__ emb,
                                            const float* __restrict__ fc1w,
                                            const float* __restrict__ fc1b,
                                            const float* __restrict__ bnfg,
                                            const float* __restrict__ bnfb,
                                            const float* __restrict__ fc2w,
                                            const float* __restrict__ fc2b,
                                            float* __restrict__ dout) {
    __shared__ float es[256];
    __shared__ float zs[1024];
    int tid = threadIdx.x;
    es[tid] = emb[tid];
    __syncthreads();
    float inv = rsqrtf(1.0f + 1e-5f);
    #pragma unroll
    for (int rep = 0; rep < 4; rep++) {
        int idx = tid + rep * 256;
        int b = idx >> 7, j = idx & 127;
        float a = fc1b[j];
        #pragma unroll
        for (int k = 0; k < 32; k++) a = fmaf(es[b * 32 + k], fc1w[k * 128 + j], a);
        a = a * (bnfg[j] * inv) + bnfb[j];
        zs[idx] = fmaxf(a, 0.f);
    }
    __syncthreads();
    if (tid < 16) {
        int b = tid >> 1, o = tid & 1;
        float a = fc2b[o];
        for (int k = 0; k < 128; k++) a = fmaf(zs[b * 128 + k], fc2w[k * 2 + o], a);
        dout[b * 2 + o] = a;
    }
}

// ---------------- launch ----------------
extern "C" void kernel_launch(void* const* d_in, const int* in_sizes, int n_in,
                              void* d_out, int out_size, void* d_ws, size_t ws_size,
                              hipStream_t stream) {
    (void)in_sizes; (void)n_in; (void)out_size; (void)ws_size;
    const float* x       = (const float*)d_in[0];
    const float* sinc_w  = (const float*)d_in[1];
    const float* conv1_w = (const float*)d_in[2];
    const float* conv1_b = (const float*)d_in[3];
    const float* bn1_g   = (const float*)d_in[4];
    const float* bn1_b   = (const float*)d_in[5];
    const float* conv2_w = (const float*)d_in[6];
    const float* conv2_b = (const float*)d_in[7];
    const float* bn2_g   = (const float*)d_in[8];
    const float* bn2_b   = (const float*)d_in[9];
    const float* gat1_W  = (const float*)d_in[10];
    const float* gat1_as = (const float*)d_in[11];
    const float* gat1_ad = (const float*)d_in[12];
    const float* gat1_bi = (const float*)d_in[13];
    const float* gat2_W  = (const float*)d_in[14];
    const float* gat2_as = (const float*)d_in[15];
    const float* gat2_ad = (const float*)d_in[16];
    const float* gat2_bi = (const float*)d_in[17];
    const float* fc1_w   = (const float*)d_in[18];
    const float* fc1_b   = (const float*)d_in[19];
    const float* bnf_g   = (const float*)d_in[20];
    const float* bnf_b   = (const float*)d_in[21];
    const float* fc2_w   = (const float*)d_in[22];
    const float* fc2_b   = (const float*)d_in[23];
    float* dout = (float*)d_out;

    float* ws = (float*)d_ws;
    unsigned short* fh  = (unsigned short*)ws;                 // 2048*1024 ush
    unsigned short* fl  = fh + (size_t)MPAD * 1024;
    unsigned short* bch = fl + (size_t)MPAD * 1024;
    unsigned short* bcl = bch + (size_t)NBPAD * 1024;
    unsigned short* bsh = bcl + (size_t)NBPAD * 1024;
    unsigned short* bsl = bsh + (size_t)NBPAD * 1024;
    float* S0   = (float*)(bsl + (size_t)NBPAD * 1024);        // 1,030,104 f
    unsigned short* wbt = (unsigned short*)(S0 + 1030104);     // 32*1056 ush
    float* w1f  = (float*)(wbt + 32 * 1056);
    float* b1f  = w1f + 288;
    float* w2f  = b1f + 32;
    float* b2f  = w2f + 9216;
    unsigned short* bpk = (unsigned short*)(b2f + 32);         // 9,216 ush
    unsigned short* Wt  = (unsigned short*)(b2f + 32 + 4608);  // 512*KPAD ush
    unsigned short* nodesb = Wt + (size_t)512 * KPAD;          // 2000*KPAD ush
    float* h1    = (float*)(nodesb + (size_t)2000 * KPAD);     // 1,024,000
    float* ssrc1 = h1 + 1024000;
    float* sdst1 = ssrc1 + 16000;
    float* smax1 = sdst1 + 16000;
    float* g1    = smax1 + 64;
    float* h2    = g1 + 1024000;
    float* s2src = h2 + 64000;
    float* s2dst = s2src + 2000;
    float* smax2 = s2dst + 2000;
    float* g2    = smax2 + 8;
    float* embp  = g2 + 64000;
    unsigned short* o1g = (unsigned short*)(embp + 256);       // 8*513*251*32 ush
    unsigned short* Pn  = o1g + (size_t)8 * 513 * 251 * 32;    // 64*256*256 ush
    unsigned short* h1t = Pn + (size_t)64 * 256 * 256;         // 64*64*256 ush
    float* hpart = (float*)(h1t + (size_t)64 * 64 * 256);      // 4*1,024,000 f
    float* dftR  = hpart + 4 * 1024000;                        // 4*MPAD*NBPAD f
    float* dftI  = dftR + (size_t)4 * MPAD * NBPAD;            // 4*MPAD*NBPAD f

    hipLaunchKernelGGL(k_fold, dim3(38), dim3(256), 0, stream,
                       conv1_w, conv1_b, bn1_g, bn1_b, conv2_w, conv2_b, bn2_g, bn2_b,
                       w1f, b1f, w2f, b2f);
    hipLaunchKernelGGL(k_pack, dim3(36), dim3(256), 0, stream, w2f, bpk);
    hipLaunchKernelGGL(k_wt, dim3(65, 8), dim3(256), 0, stream, gat1_W, Wt);
    hipLaunchKernelGGL(k_wbt, dim3((32 * 1056 + 255) / 256), dim3(256), 0, stream, sinc_w, wbt);
    hipLaunchKernelGGL(k_basis_bf, dim3(NBPAD * 1024 / 256), dim3(256), 0, stream,
                       bch, bcl, bsh, bsl);
    hipLaunchKernelGGL(k_frames_bf, dim3(MPAD * 1024 / 256), dim3(256), 0, stream, x, fh, fl);
    hipLaunchKernelGGL(k_dft_mfma, dim3(9, 32, 4), dim3(256), 0, stream,
                       fh, fl, bch, bcl, bsh, bsl, dftR, dftI);
    hipLaunchKernelGGL(k_dftred, dim3((NROWS * NBINS + 255) / 256), dim3(256), 0, stream,
                       dftR, dftI, S0);
    hipLaunchKernelGGL(k_sincm, dim3(8), dim3(256), 0, stream, x, wbt, nodesb);
    hipLaunchKernelGGL(k_conv1, dim3(513, 8), dim3(256), 0, stream, S0, w1f, b1f, o1g);
    hipLaunchKernelGGL(k_conv2m, dim3(8, 32, 8), dim3(256), 0, stream, o1g, bpk, b2f, nodesb);
    hipLaunchKernelGGL(k_gat1s, dim3(8, 32, 4), dim3(256), 0, stream, nodesb, Wt, hpart);
    hipLaunchKernelGGL(k_hred, dim3(4000), dim3(256), 0, stream, hpart, h1, h1t);
    hipLaunchKernelGGL(k_scores1, dim3(500), dim3(256), 0, stream, h1, gat1_as, gat1_ad, ssrc1, sdst1);
    hipLaunchKernelGGL(k_smax1, dim3(64), dim3(64), 0, stream, ssrc1, smax1);
    hipLaunchKernelGGL(k_attw, dim3(64), dim3(256), 0, stream, ssrc1, sdst1, smax1, Pn);
    hipLaunchKernelGGL(k_attnv, dim3(64), dim3(256), 0, stream, Pn, h1t, gat1_bi, g1);
    hipLaunchKernelGGL(k_h2, dim3(500), dim3(256), 0, stream,
                       g1, gat2_W, gat2_as, gat2_ad, h2, s2src, s2dst);
    hipLaunchKernelGGL(k_smax2, dim3(8), dim3(64), 0, stream, s2src, smax2);
    hipLaunchKernelGGL(k_attn2, dim3(63, 8), dim3(256), 0, stream,
                       h2, s2src, s2dst, smax2, gat2_bi, g2);
    hipLaunchKernelGGL(k_emb, dim3(8), dim3(256), 0, stream, g2, embp, dout);
    hipLaunchKernelGGL(k_fc, dim3(1), dim3(256), 0, stream,
                       embp, fc1_w, fc1_b, bnf_g, bnf_b, fc2_w, fc2_b, dout);
}

// Round 13
// 398.875 us; speedup vs baseline: 1.0177x; 1.0177x over previous
//
#include <hip/hip_runtime.h>
#include <hip/hip_bf16.h>
#include <math.h>

// ---------------- constants ----------------
#define TB 8
#define TT 64000
#define NFRAMES 251
#define NROWS (TB*NFRAMES)      // 2008
#define MPAD 2048
#define NBINS 513
#define NBPAD 576
#define NNODE 250
#define NODE_DIM 4116
#define KPAD 4128

typedef __attribute__((ext_vector_type(8))) short short8;
typedef __attribute__((ext_vector_type(4))) float floatx4;

static __device__ __forceinline__ unsigned short f2bf(float x) {
    __hip_bfloat16 h = __float2bfloat16(x);
    return *(unsigned short*)&h;
}
static __device__ __forceinline__ float bf2f(unsigned short u) {
    __hip_bfloat16 h = *(__hip_bfloat16*)&u;
    return __bfloat162float(h);
}

// ---------------- small prep kernels ----------------

__global__ void k_fold(const float* __restrict__ c1w, const float* __restrict__ c1b,
                       const float* __restrict__ g1bn, const float* __restrict__ b1bn,
                       const float* __restrict__ c2w, const float* __restrict__ c2b,
                       const float* __restrict__ g2bn, const float* __restrict__ b2bn,
                       float* __restrict__ w1f, float* __restrict__ b1f,
                       float* __restrict__ w2f, float* __restrict__ b2f) {
    int idx = blockIdx.x * 256 + threadIdx.x;
    float inv = rsqrtf(1.0f + 1e-5f);
    if (idx < 9216) {
        int co = idx / 288;
        w2f[idx] = c2w[idx] * (g2bn[co] * inv);
    } else if (idx < 9216 + 288) {
        int r = idx - 9216;
        w1f[r] = c1w[r] * (g1bn[r / 9] * inv);
    } else if (idx < 9216 + 288 + 32) {
        int c = idx - 9504;
        b1f[c] = c1b[c] * (g1bn[c] * inv) + b1bn[c];
    } else if (idx < 9216 + 288 + 64) {
        int c = idx - 9536;
        b2f[c] = c2b[c] * (g2bn[c] * inv) + b2bn[c];
    }
}

// pack conv2 weights into MFMA B-fragment order, bf16.
__global__ void k_pack(const float* __restrict__ w2f, unsigned short* __restrict__ Bp) {
    int idx = blockIdx.x * 256 + threadIdx.x;
    if (idx >= 9216) return;
    int j = idx & 7, lane = (idx >> 3) & 63, ct = (idx >> 9) & 1, s = idx >> 10;
    int co = ct * 16 + (lane & 15);
    int ci = (lane >> 4) * 8 + j;
    Bp[idx] = f2bf(w2f[co * 288 + ci * 9 + s]);
}

// transpose gat1_W -> Wt [512][KPAD] bf16 with K-permutation:
// dest k' = 20 + f*16 + c  <->  source k = 20 + c*256 + f  (c<16, f<256); k<20 identity
__global__ __launch_bounds__(256) void k_wt(const float* __restrict__ W,
                                            unsigned short* __restrict__ Wt) {
    __shared__ unsigned short tile[64][65];
    int kt = blockIdx.x, nt = blockIdx.y;
    int tid = threadIdx.x;
    for (int idx = tid; idx < 4096; idx += 256) {
        int r = idx >> 6, c = idx & 63;
        int kp = kt * 64 + r;
        int k;
        if (kp < 20) k = kp;
        else if (kp < NODE_DIM) { int t = kp - 20; k = 20 + (t & 15) * 256 + (t >> 4); }
        else k = -1;
        float v = (k >= 0) ? W[k * 512 + nt * 64 + c] : 0.f;
        tile[r][c] = f2bf(v);
    }
    __syncthreads();
    for (int idx = tid; idx < 4096; idx += 256) {
        int nl = idx >> 6, kl = idx & 63;
        int k = kt * 64 + kl;
        if (k < KPAD)
            Wt[(size_t)(nt * 64 + nl) * KPAD + k] = tile[kl][nl];
    }
}

// sinc weights: 4-tap prefix-summed, transposed, padded bf16: wbt[32][1056]
__global__ void k_wbt(const float* __restrict__ sw, unsigned short* __restrict__ wbt) {
    int idx = blockIdx.x * 256 + threadIdx.x;
    if (idx >= 32 * 1056) return;
    int c = idx / 1056, m = idx - c * 1056;
    float s = 0.f;
    if (c < 20 && m < 1027) {
        #pragma unroll
        for (int d = 0; d < 4; d++) {
            int k = m - d;
            if (k >= 0 && k < 1024) s += sw[c * 1024 + k];
        }
        s *= 0.25f;
    }
    wbt[idx] = f2bf(s);
}

// DFT basis, bf16 hi/lo split; rows [NBINS..NBPAD) zero
__global__ void k_basis_bf(unsigned short* __restrict__ ch, unsigned short* __restrict__ cl,
                           unsigned short* __restrict__ sh, unsigned short* __restrict__ sl) {
    int idx = blockIdx.x * 256 + threadIdx.x;
    if (idx >= NBPAD * 1024) return;
    int k = idx >> 10, n = idx & 1023;
    float s = 0.f, c = 0.f;
    if (k < NBINS) {
        int mm = (k * n) & 1023;
        sincospif((float)mm * (1.0f / 512.0f), &s, &c);
    }
    unsigned short chv = f2bf(c), shv = f2bf(s);
    ch[idx] = chv; cl[idx] = f2bf(c - bf2f(chv));
    sh[idx] = shv; sl[idx] = f2bf(s - bf2f(shv));
}

// frames (reflect-padded) -> bf16 hi/lo, rows [NROWS..MPAD) zero
__global__ void k_frames_bf(const float* __restrict__ x,
                            unsigned short* __restrict__ fh, unsigned short* __restrict__ fl) {
    int idx = blockIdx.x * 256 + threadIdx.x;
    if (idx >= MPAD * 1024) return;
    int m = idx >> 10, n = idx & 1023;
    float v = 0.f;
    if (m < NROWS) {
        int b = m / NFRAMES, i = m - b * NFRAMES;
        int j = i * 256 + n - 512;
        if (j < 0) j = -j;
        if (j >= TT) j = 2 * TT - 2 - j;
        v = x[b * TT + j];
    }
    unsigned short h = f2bf(v);
    fh[idx] = h;
    fl[idx] = f2bf(v - bf2f(h));
}

// ---------------- sinc conv as MFMA GEMM, M-split: nodes[b][u][0..19] ----------------
// grid (4, 8): blockIdx.x = u-tile (64 nodes), blockIdx.y = batch
__global__ __launch_bounds__(256) void k_sincm(const float* __restrict__ x,
                                               const unsigned short* __restrict__ wbt,
                                               unsigned short* __restrict__ nodesb) {
    __shared__ __align__(16) unsigned short xs[1312];
    int ut = blockIdx.x, b = blockIdx.y;
    int tid = threadIdx.x;
    int base = 256 * ut - 512;
    for (int i = tid; i < 1312; i += 256) {
        int g = base + i;
        float v = (g >= 0 && g < TT) ? x[b * TT + g] : 0.f;
        xs[i] = f2bf(v);
    }
    __syncthreads();
    int w = tid >> 6, lane = tid & 63;
    int q = lane >> 4, col = lane & 15;
    floatx4 acc[2];
    acc[0] = acc[1] = (floatx4){0.f, 0.f, 0.f, 0.f};
    for (int K0 = 0; K0 < 1056; K0 += 32) {
        int off = 4 * (w * 16 + col) + K0 + q * 8;
        unsigned long long lo = *(const unsigned long long*)&xs[off];
        unsigned long long hi = *(const unsigned long long*)&xs[off + 4];
        union { unsigned long long u64[2]; short8 s8; } cv;
        cv.u64[0] = lo; cv.u64[1] = hi;
        short8 af = cv.s8;
        #pragma unroll
        for (int ni = 0; ni < 2; ni++) {
            short8 bf = *(const short8*)(wbt + (size_t)(ni * 16 + col) * 1056 + K0 + q * 8);
            acc[ni] = __builtin_amdgcn_mfma_f32_16x16x32_bf16(af, bf, acc[ni], 0, 0, 0);
        }
    }
    #pragma unroll
    for (int ni = 0; ni < 2; ni++)
        #pragma unroll
        for (int rr = 0; rr < 4; rr++) {
            int u = ut * 64 + w * 16 + q * 4 + rr;
            int c = ni * 16 + col;
            if (u < NNODE && c < 20)
                nodesb[(size_t)(b * NNODE + u) * KPAD + c] = f2bf(acc[ni][rr]);
        }
}

// ---------------- DFT via bf16 MFMA, single-pass, 32-row M tiles ----------------
// grid (9, 64): N0 = bx*64, M0 = by*32. LDS 25.6 KB -> 2 blocks/CU.
__global__ __launch_bounds__(256) void k_dft_mfma(const unsigned short* __restrict__ fh,
                                                  const unsigned short* __restrict__ fl,
                                                  const unsigned short* __restrict__ ch,
                                                  const unsigned short* __restrict__ cl,
                                                  const unsigned short* __restrict__ sh,
                                                  const unsigned short* __restrict__ sl,
                                                  float* __restrict__ S0) {
    __shared__ __align__(16) unsigned short Ah[32 * 40];
    __shared__ __align__(16) unsigned short Al[32 * 40];
    __shared__ __align__(16) unsigned short Bch[64 * 40];
    __shared__ __align__(16) unsigned short Bcl[64 * 40];
    __shared__ __align__(16) unsigned short Bsh[64 * 40];
    __shared__ __align__(16) unsigned short Bsl[64 * 40];
    int tid = threadIdx.x;
    int N0 = blockIdx.x * 64, M0 = blockIdx.y * 32;
    int br = tid >> 2, bc = (tid & 3) * 8;
    size_t boff = (size_t)(N0 + br) * 1024 + bc;
    int ar = (tid & 127) >> 2, ac = (tid & 3) * 8;
    size_t aoff = (size_t)(M0 + ar) * 1024 + ac;
    bool loA = tid < 128;
    int w = tid >> 6, lane = tid & 63;
    int q = lane >> 4, col = lane & 15;
    int mb = (w >> 1) * 16, nb = (w & 1) * 32;
    floatx4 aR[2], aI[2];
    aR[0] = aR[1] = aI[0] = aI[1] = (floatx4){0.f, 0.f, 0.f, 0.f};

    for (int K0 = 0; K0 < 1024; K0 += 32) {
        if (loA) *(short8*)&Ah[ar * 40 + ac] = *(const short8*)(fh + aoff + K0);
        else     *(short8*)&Al[ar * 40 + ac] = *(const short8*)(fl + aoff + K0);
        *(short8*)&Bch[br * 40 + bc] = *(const short8*)(ch + boff + K0);
        *(short8*)&Bcl[br * 40 + bc] = *(const short8*)(cl + boff + K0);
        *(short8*)&Bsh[br * 40 + bc] = *(const short8*)(sh + boff + K0);
        *(short8*)&Bsl[br * 40 + bc] = *(const short8*)(sl + boff + K0);
        __syncthreads();
        short8 ahv = *(const short8*)&Ah[(mb + col) * 40 + q * 8];
        short8 alv = *(const short8*)&Al[(mb + col) * 40 + q * 8];
        #pragma unroll
        for (int ni = 0; ni < 2; ni++) {
            short8 chv = *(const short8*)&Bch[(nb + ni * 16 + col) * 40 + q * 8];
            short8 clv = *(const short8*)&Bcl[(nb + ni * 16 + col) * 40 + q * 8];
            short8 shv = *(const short8*)&Bsh[(nb + ni * 16 + col) * 40 + q * 8];
            short8 slv = *(const short8*)&Bsl[(nb + ni * 16 + col) * 40 + q * 8];
            aR[ni] = __builtin_amdgcn_mfma_f32_16x16x32_bf16(ahv, chv, aR[ni], 0, 0, 0);
            aR[ni] = __builtin_amdgcn_mfma_f32_16x16x32_bf16(ahv, clv, aR[ni], 0, 0, 0);
            aR[ni] = __builtin_amdgcn_mfma_f32_16x16x32_bf16(alv, chv, aR[ni], 0, 0, 0);
            aI[ni] = __builtin_amdgcn_mfma_f32_16x16x32_bf16(ahv, shv, aI[ni], 0, 0, 0);
            aI[ni] = __builtin_amdgcn_mfma_f32_16x16x32_bf16(ahv, slv, aI[ni], 0, 0, 0);
            aI[ni] = __builtin_amdgcn_mfma_f32_16x16x32_bf16(alv, shv, aI[ni], 0, 0, 0);
        }
        __syncthreads();
    }
    #pragma unroll
    for (int ni = 0; ni < 2; ni++)
        #pragma unroll
        for (int rr = 0; rr < 4; rr++) {
            int m = M0 + mb + q * 4 + rr;
            int bin = N0 + nb + ni * 16 + col;
            if (m < NROWS && bin < NBINS) {
                float re = aR[ni][rr], im = aI[ni][rr];
                int b = m / NFRAMES, i = m - b * NFRAMES;
                S0[(b * NBINS + bin) * NFRAMES + i] =
                    logf(sqrtf(fmaf(re, re, im * im)) + 1e-9f);
            }
        }
}

// ---------------- conv1+BN+ReLU -> o1g[b][513][251][32] bf16 channels-last ----------------
__global__ __launch_bounds__(256) void k_conv1(const float* __restrict__ S0,
                                               const float* __restrict__ w1f,
                                               const float* __restrict__ b1f,
                                               unsigned short* __restrict__ o1g) {
    __shared__ float w1s[288];
    __shared__ float b1s[32];
    int tid = threadIdx.x;
    for (int i = tid; i < 288; i += 256) w1s[i] = w1f[i];
    if (tid < 32) b1s[tid] = b1f[tid];
    __syncthreads();
    int r = blockIdx.x;
    int b = blockIdx.y;
    int t = tid;
    if (t >= 251) return;
    float sv[9];
    #pragma unroll
    for (int di = 0; di < 3; di++) {
        int rr = r - 1 + di;
        #pragma unroll
        for (int dj = 0; dj < 3; dj++) {
            int tt = t - 1 + dj;
            float v = 0.f;
            if (rr >= 0 && rr < 513 && tt >= 0 && tt < 251)
                v = S0[(b * 513 + rr) * 251 + tt];
            sv[di * 3 + dj] = v;
        }
    }
    unsigned short ov[32];
    #pragma unroll
    for (int ci = 0; ci < 32; ci++) {
        float a = b1s[ci];
        const float* wp = &w1s[ci * 9];
        #pragma unroll
        for (int k = 0; k < 9; k++) a = fmaf(sv[k], wp[k], a);
        ov[ci] = f2bf(fmaxf(a, 0.f));
    }
    unsigned short* dst = o1g + ((size_t)(b * 513 + r) * 251 + t) * 32;
    #pragma unroll
    for (int i = 0; i < 4; i++)
        *(short8*)(dst + i * 8) = *(const short8*)&ov[i * 8];
}

// ---------------- conv2: wide LDS tile, MFMA from LDS, pool, coalesced store ----------------
__global__ __launch_bounds__(256) void k_conv2m(const unsigned short* __restrict__ o1g,
                                                const unsigned short* __restrict__ Bp,
                                                const float* __restrict__ b2f,
                                                unsigned short* __restrict__ nodesb) {
    __shared__ __align__(16) unsigned short o1s[18 * 34 * 32];
    __shared__ float b2s[32];
    int tid = threadIdx.x;
    int b = blockIdx.z;
    int F0 = blockIdx.y * 8;
    int T0 = blockIdx.x * 16;
    if (tid < 32) b2s[tid] = b2f[tid];
    short8 z8 = {0, 0, 0, 0, 0, 0, 0, 0};
    const unsigned short* ob = o1g + (size_t)b * 513 * 251 * 32;

    for (int idx = tid; idx < 2448; idx += 256) {
        int r = idx / 136, rem = idx - r * 136;
        int t = rem >> 2, o = rem & 3;
        int r1 = 2 * F0 - 1 + r, t1 = 2 * T0 - 1 + t;
        short8 v = z8;
        if (r1 >= 0 && r1 < 513 && t1 >= 0 && t1 < 251)
            v = *(const short8*)(ob + ((size_t)r1 * 251 + t1) * 32 + o * 8);
        *(short8*)&o1s[(r * 34 + t) * 32 + o * 8] = v;
    }
    __syncthreads();

    int lane = tid & 63, w = tid >> 6;
    int q = lane >> 4, col = lane & 15;
    floatx4 acc[2][4][2];
    #pragma unroll
    for (int tt = 0; tt < 2; tt++)
        #pragma unroll
        for (int rt = 0; rt < 4; rt++)
            #pragma unroll
            for (int ct = 0; ct < 2; ct++)
                acc[tt][rt][ct] = (floatx4){0.f, 0.f, 0.f, 0.f};

    #pragma unroll
    for (int s = 0; s < 9; s++) {
        const int di = s / 3, dj = s % 3;
        short8 bf0 = *(const short8*)&Bp[(s * 2 + 0) * 512 + lane * 8];
        short8 bf1 = *(const short8*)&Bp[(s * 2 + 1) * 512 + lane * 8];
        #pragma unroll
        for (int tt = 0; tt < 2; tt++)
            #pragma unroll
            for (int rt = 0; rt < 4; rt++) {
                short8 af = *(const short8*)&o1s[((w * 4 + rt + di) * 34 + (col + tt * 16 + dj)) * 32 + q * 8];
                acc[tt][rt][0] = __builtin_amdgcn_mfma_f32_16x16x32_bf16(af, bf0, acc[tt][rt][0], 0, 0, 0);
                acc[tt][rt][1] = __builtin_amdgcn_mfma_f32_16x16x32_bf16(af, bf1, acc[tt][rt][1], 0, 0, 0);
            }
    }
    __syncthreads();

    unsigned short* nb = o1s;
    #pragma unroll
    for (int tt = 0; tt < 2; tt++)
        #pragma unroll
        for (int ct = 0; ct < 2; ct++) {
            float bb = b2s[ct * 16 + col];
            #pragma unroll
            for (int fp2 = 0; fp2 < 2; fp2++)
                #pragma unroll
                for (int tc2 = 0; tc2 < 2; tc2++) {
                    float m0 = fmaxf(
                        fmaxf(acc[tt][2 * fp2][ct][2 * tc2], acc[tt][2 * fp2][ct][2 * tc2 + 1]),
                        fmaxf(acc[tt][2 * fp2 + 1][ct][2 * tc2], acc[tt][2 * fp2 + 1][ct][2 * tc2 + 1]));
                    float v = fmaxf(m0 + bb, 0.f);
                    int nl = (tt * 8 + 2 * q + tc2) * 2 + ct;
                    int fl = 2 * w + fp2;
                    nb[nl * 136 + fl * 16 + col] = f2bf(v);
                }
        }
    __syncthreads();

    int nl = tid >> 3, part = tid & 7;
    int node_g = 2 * T0 + nl;
    if (node_g < NNODE) {
        unsigned short* dst = nodesb + (size_t)(b * NNODE + node_g) * KPAD + 20 + F0 * 16 + part * 16;
        *(short8*)(dst)     = *(const short8*)&nb[nl * 136 + part * 16];
        *(short8*)(dst + 8) = *(const short8*)&nb[nl * 136 + part * 16 + 8];
    }
}

// ---------------- GAT1 GEMM split-K (bf16 MFMA): hpart[kc][2000][512] ----------------
__global__ __launch_bounds__(256) void k_gat1s(const unsigned short* __restrict__ A,
                                               const unsigned short* __restrict__ Bt,
                                               float* __restrict__ hpart) {
    __shared__ __align__(16) unsigned short As[64 * 40];
    __shared__ __align__(16) unsigned short Bs[64 * 40];
    int tid = threadIdx.x;
    int N0 = blockIdx.x * 64, M0 = blockIdx.y * 64;
    int kc = blockIdx.z;
    int ks = (kc == 0) ? 0 : (33 + 32 * (kc - 1));
    int ke = 33 + 32 * kc;
    if (kc == 0) ke = 33;
    int sr = tid >> 2, sc = (tid & 3) * 8;
    int w = tid >> 6, lane = tid & 63;
    int q = lane >> 4, col = lane & 15;
    int mb = (w >> 1) * 32, nb = (w & 1) * 32;
    floatx4 acc[2][2];
    acc[0][0] = acc[0][1] = acc[1][0] = acc[1][1] = (floatx4){0.f, 0.f, 0.f, 0.f};
    short8 z8 = {0, 0, 0, 0, 0, 0, 0, 0};
    int mA = M0 + sr;
    bool mv = mA < 2000;
    const unsigned short* pa = A + (size_t)mA * KPAD + sc;
    const unsigned short* pb = Bt + (size_t)(N0 + sr) * KPAD + sc;

    for (int kk = ks; kk < ke; kk++) {
        int K0 = kk * 32;
        short8 va = mv ? *(const short8*)(pa + K0) : z8;
        short8 vb = *(const short8*)(pb + K0);
        *(short8*)&As[sr * 40 + sc] = va;
        *(short8*)&Bs[sr * 40 + sc] = vb;
        __syncthreads();
        short8 a0 = *(const short8*)&As[(mb + col) * 40 + q * 8];
        short8 a1 = *(const short8*)&As[(mb + 16 + col) * 40 + q * 8];
        short8 b0 = *(const short8*)&Bs[(nb + col) * 40 + q * 8];
        short8 b1 = *(const short8*)&Bs[(nb + 16 + col) * 40 + q * 8];
        acc[0][0] = __builtin_amdgcn_mfma_f32_16x16x32_bf16(a0, b0, acc[0][0], 0, 0, 0);
        acc[0][1] = __builtin_amdgcn_mfma_f32_16x16x32_bf16(a0, b1, acc[0][1], 0, 0, 0);
        acc[1][0] = __builtin_amdgcn_mfma_f32_16x16x32_bf16(a1, b0, acc[1][0], 0, 0, 0);
        acc[1][1] = __builtin_amdgcn_mfma_f32_16x16x32_bf16(a1, b1, acc[1][1], 0, 0, 0);
        __syncthreads();
    }
    float* out = hpart + (size_t)kc * 1024000;
    #pragma unroll
    for (int mi = 0; mi < 2; mi++)
        #pragma unroll
        for (int ni = 0; ni < 2; ni++)
            #pragma unroll
            for (int rr = 0; rr < 4; rr++) {
                int m = M0 + mb + mi * 16 + q * 4 + rr;
                if (m < 2000)
                    out[m * 512 + N0 + nb + ni * 16 + col] = acc[mi][ni][rr];
            }
}

// reduce 4 partials -> h1 f32 + h1t bf16 [bh][f][256]
__global__ __launch_bounds__(256) void k_hred(const float* __restrict__ hpart,
                                              float* __restrict__ h1,
                                              unsigned short* __restrict__ h1t) {
    int idx = blockIdx.x * 256 + threadIdx.x;
    if (idx >= 1024000) return;
    float s = hpart[idx] + hpart[idx + 1024000] + hpart[idx + 2048000] + hpart[idx + 3072000];
    h1[idx] = s;
    int m = idx >> 9, n = idx & 511;
    int bb = m / NNODE, j = m - bb * NNODE;
    int hh = n >> 6, f = n & 63;
    h1t[((size_t)((bb * 8 + hh) * 64 + f)) * 256 + j] = f2bf(s);
}

// ---------------- GAT1 scores / max ----------------
__global__ __launch_bounds__(256) void k_scores1(const float* __restrict__ h1,
                                                 const float* __restrict__ asrc,
                                                 const float* __restrict__ adst,
                                                 float* __restrict__ ssrc,
                                                 float* __restrict__ sdst) {
    int row = blockIdx.x * 4 + (threadIdx.x >> 6);
    int lane = threadIdx.x & 63;
    if (row >= 2000) return;
    for (int h = 0; h < 8; h++) {
        float v = h1[row * 512 + h * 64 + lane];
        float ps = v * asrc[h * 64 + lane];
        float pd = v * adst[h * 64 + lane];
        for (int off = 32; off > 0; off >>= 1) {
            ps += __shfl_down(ps, off);
            pd += __shfl_down(pd, off);
        }
        if (lane == 0) { ssrc[row * 8 + h] = ps; sdst[row * 8 + h] = pd; }
    }
}

__global__ __launch_bounds__(64) void k_smax1(const float* __restrict__ ssrc,
                                              float* __restrict__ smax) {
    int bh = blockIdx.x;
    int b = bh >> 3, h = bh & 7;
    int lane = threadIdx.x;
    float m = -1e30f;
    for (int n = lane; n < NNODE; n += 64) m = fmaxf(m, ssrc[(b * NNODE + n) * 8 + h]);
    for (int off = 32; off > 0; off >>= 1) m = fmaxf(m, __shfl_down(m, off));
    if (lane == 0) smax[bh] = m;
}

// ---------------- GAT1 attention weights: Pn[bh][256][256] bf16 normalized ----------------
__global__ __launch_bounds__(256) void k_attw(const float* __restrict__ ssrc,
                                              const float* __restrict__ sdst,
                                              const float* __restrict__ smax,
                                              unsigned short* __restrict__ Pn) {
    int bh = blockIdx.x;
    int b = bh >> 3, h = bh & 7;
    int tid = threadIdx.x;
    __shared__ float ss[NNODE];
    for (int j = tid; j < NNODE; j += 256) ss[j] = ssrc[(b * NNODE + j) * 8 + h];
    __syncthreads();
    unsigned short* row = Pn + ((size_t)bh * 256 + tid) * 256;
    short8 z8 = {0, 0, 0, 0, 0, 0, 0, 0};
    if (tid >= NNODE) {
        #pragma unroll
        for (int j = 0; j < 256; j += 8) *(short8*)(row + j) = z8;
        return;
    }
    float d = sdst[(b * NNODE + tid) * 8 + h];
    float e0 = d + smax[bh];
    float mx = e0 > 0.f ? e0 : 0.2f * e0;
    float den = 0.f;
    for (int j = 0; j < NNODE; j++) {
        float e = d + ss[j];
        e = e > 0.f ? e : 0.2f * e;
        den += __expf(e - mx);
    }
    float rden = 1.f / den;
    for (int j0 = 0; j0 < 256; j0 += 8) {
        unsigned short wv[8];
        #pragma unroll
        for (int jj = 0; jj < 8; jj++) {
            int j = j0 + jj;
            float wt = 0.f;
            if (j < NNODE) {
                float e = d + ss[j];
                e = e > 0.f ? e : 0.2f * e;
                wt = __expf(e - mx) * rden;
            }
            wv[jj] = f2bf(wt);
        }
        *(short8*)(row + j0) = *(const short8*)wv;
    }
}

// ---------------- GAT1 attention apply (MFMA): g1 = Pn @ h1t^T + bias, relu ----------------
__global__ __launch_bounds__(256) void k_attnv(const unsigned short* __restrict__ Pn,
                                               const unsigned short* __restrict__ h1t,
                                               const float* __restrict__ bias,
                                               float* __restrict__ g1) {
    int bh = blockIdx.x;
    int b = bh >> 3, h = bh & 7;
    int tid = threadIdx.x;
    int w = tid >> 6, lane = tid & 63;
    int q = lane >> 4, col = lane & 15;
    const unsigned short* Pb = Pn + (size_t)bh * 65536;
    const unsigned short* Hb = h1t + (size_t)bh * 16384;
    floatx4 acc[4][4];
    #pragma unroll
    for (int mi = 0; mi < 4; mi++)
        #pragma unroll
        for (int ni = 0; ni < 4; ni++)
            acc[mi][ni] = (floatx4){0.f, 0.f, 0.f, 0.f};
    for (int k0 = 0; k0 < 256; k0 += 32) {
        short8 af[4], bf[4];
        #pragma unroll
        for (int mi = 0; mi < 4; mi++)
            af[mi] = *(const short8*)(Pb + (size_t)((w * 4 + mi) * 16 + col) * 256 + k0 + q * 8);
        #pragma unroll
        for (int ni = 0; ni < 4; ni++)
            bf[ni] = *(const short8*)(Hb + (size_t)(ni * 16 + col) * 256 + k0 + q * 8);
        #pragma unroll
        for (int mi = 0; mi < 4; mi++)
            #pragma unroll
            for (int ni = 0; ni < 4; ni++)
                acc[mi][ni] = __builtin_amdgcn_mfma_f32_16x16x32_bf16(af[mi], bf[ni], acc[mi][ni], 0, 0, 0);
    }
    #pragma unroll
    for (int mi = 0; mi < 4; mi++)
        #pragma unroll
        for (int ni = 0; ni < 4; ni++)
            #pragma unroll
            for (int rr = 0; rr < 4; rr++) {
                int i = (w * 4 + mi) * 16 + q * 4 + rr;
                int f = ni * 16 + col;
                if (i < NNODE)
                    g1[(b * NNODE + i) * 512 + h * 64 + f] =
                        fmaxf(acc[mi][ni][rr] + bias[h * 64 + f], 0.f);
            }
}

// ---------------- GAT2 ----------------
__global__ __launch_bounds__(256) void k_h2(const float* __restrict__ g1,
                                            const float* __restrict__ W2,
                                            const float* __restrict__ a2src,
                                            const float* __restrict__ a2dst,
                                            float* __restrict__ h2,
                                            unsigned short* __restrict__ h2t,
                                            float* __restrict__ s2src,
                                            float* __restrict__ s2dst) {
    int row = blockIdx.x * 4 + (threadIdx.x >> 6);
    if (row >= 2000) return;
    int lane = threadIdx.x & 63;
    int o = lane & 31, half = lane >> 5;
    const float* gr = &g1[row * 512 + half * 256];
    float acc = 0.f;
    for (int k = 0; k < 256; k++) acc = fmaf(gr[k], W2[(half * 256 + k) * 32 + o], acc);
    acc += __shfl_down(acc, 32);
    float ps = acc * a2src[o], pd = acc * a2dst[o];
    for (int off = 16; off > 0; off >>= 1) {
        ps += __shfl_down(ps, off, 32);
        pd += __shfl_down(pd, off, 32);
    }
    if (lane == 0) { s2src[row] = ps; s2dst[row] = pd; }
    if (lane < 32) {
        h2[row * 32 + o] = acc;
        int b = row / NNODE, j = row - b * NNODE;
        h2t[((size_t)(b * 32 + o)) * 256 + j] = f2bf(acc);
    }
}

__global__ __launch_bounds__(64) void k_smax2(const float* __restrict__ s2src,
                                              float* __restrict__ smax2) {
    int b = blockIdx.x, lane = threadIdx.x;
    float m = -1e30f;
    for (int n = lane; n < NNODE; n += 64) m = fmaxf(m, s2src[b * NNODE + n]);
    for (int off = 32; off > 0; off >>= 1) m = fmaxf(m, __shfl_down(m, off));
    if (lane == 0) smax2[b] = m;
}

// GAT2 attention weights: P2n[b][256][256] bf16 normalized
__global__ __launch_bounds__(256) void k_attw2(const float* __restrict__ s2src,
                                               const float* __restrict__ s2dst,
                                               const float* __restrict__ smax2,
                                               unsigned short* __restrict__ P2n) {
    int b = blockIdx.x;
    int tid = threadIdx.x;
    __shared__ float ss[NNODE];
    for (int j = tid; j < NNODE; j += 256) ss[j] = s2src[b * NNODE + j];
    __syncthreads();
    unsigned short* row = P2n + ((size_t)b * 256 + tid) * 256;
    short8 z8 = {0, 0, 0, 0, 0, 0, 0, 0};
    if (tid >= NNODE) {
        #pragma unroll
        for (int j = 0; j < 256; j += 8) *(short8*)(row + j) = z8;
        return;
    }
    float d = s2dst[b * NNODE + tid];
    float e0 = d + smax2[b];
    float mx = e0 > 0.f ? e0 : 0.2f * e0;
    float den = 0.f;
    for (int j = 0; j < NNODE; j++) {
        float e = d + ss[j];
        e = e > 0.f ? e : 0.2f * e;
        den += __expf(e - mx);
    }
    float rden = 1.f / den;
    for (int j0 = 0; j0 < 256; j0 += 8) {
        unsigned short wv[8];
        #pragma unroll
        for (int jj = 0; jj < 8; jj++) {
            int j = j0 + jj;
            float wt = 0.f;
            if (j < NNODE) {
                float e = d + ss[j];
                e = e > 0.f ? e : 0.2f * e;
                wt = __expf(e - mx) * rden;
            }
            wv[jj] = f2bf(wt);
        }
        *(short8*)(row + j0) = *(const short8*)wv;
    }
}

// GAT2 attention apply (MFMA): g2 = P2n @ h2t^T + bias2
__global__ __launch_bounds__(256) void k_attnv2(const unsigned short* __restrict__ P2n,
                                                const unsigned short* __restrict__ h2t,
                                                const float* __restrict__ bias2,
                                                float* __restrict__ g2) {
    int b = blockIdx.x;
    int tid = threadIdx.x;
    int w = tid >> 6, lane = tid & 63;
    int q = lane >> 4, col = lane & 15;
    const unsigned short* Pb = P2n + (size_t)b * 65536;
    const unsigned short* Hb = h2t + (size_t)b * 8192;
    floatx4 acc[4][2];
    #pragma unroll
    for (int mi = 0; mi < 4; mi++)
        #pragma unroll
        for (int ni = 0; ni < 2; ni++)
            acc[mi][ni] = (floatx4){0.f, 0.f, 0.f, 0.f};
    for (int k0 = 0; k0 < 256; k0 += 32) {
        short8 af[4], bf[2];
        #pragma unroll
        for (int mi = 0; mi < 4; mi++)
            af[mi] = *(const short8*)(Pb + (size_t)((w * 4 + mi) * 16 + col) * 256 + k0 + q * 8);
        #pragma unroll
        for (int ni = 0; ni < 2; ni++)
            bf[ni] = *(const short8*)(Hb + (size_t)(ni * 16 + col) * 256 + k0 + q * 8);
        #pragma unroll
        for (int mi = 0; mi < 4; mi++)
            #pragma unroll
            for (int ni = 0; ni < 2; ni++)
                acc[mi][ni] = __builtin_amdgcn_mfma_f32_16x16x32_bf16(af[mi], bf[ni], acc[mi][ni], 0, 0, 0);
    }
    #pragma unroll
    for (int mi = 0; mi < 4; mi++)
        #pragma unroll
        for (int ni = 0; ni < 2; ni++)
            #pragma unroll
            for (int rr = 0; rr < 4; rr++) {
                int i = (w * 4 + mi) * 16 + q * 4 + rr;
                int f = ni * 16 + col;
                if (i < NNODE)
                    g2[(b * NNODE + i) * 32 + f] = acc[mi][ni][rr] + bias2[f];
            }
}

__global__ __launch_bounds__(256) void k_emb(const float* __restrict__ g2,
                                             float* __restrict__ emb,
                                             float* __restrict__ dout) {
    int b = blockIdx.x;
    int f = threadIdx.x & 31, g = threadIdx.x >> 5;
    __shared__ float red[8][32];
    float s = 0.f;
    for (int i = g; i < NNODE; i += 8) s += g2[(b * NNODE + i) * 32 + f];
    red[g][f] = s;
    __syncthreads();
    if (threadIdx.x < 32) {
        float t = 0.f;
        #pragma unroll
        for (int gg = 0; gg < 8; gg++) t += red[gg][f];
        t *= (1.0f / 250.0f);
        emb[b * 32 + f] = t;
        dout[16 + b * 32 + f] = t;
    }
}

__global__ __launch_bounds__(256) void k_fc(const float* __restrict__ emb,
                                            const float* __restrict__ fc1w,
                                            const float* __restrict__ fc1b,
                                            const float* __restrict__ bnfg,
                                            const float* __restrict__ bnfb,
                                            const float* __restrict__ fc2w,
                                            const float* __restrict__ fc2b,
                                            float* __restrict__ dout) {
    __shared__ float es[256];
    __shared__ float zs[1024];
    int tid = threadIdx.x;
    es[tid] = emb[tid];
    __syncthreads();
    float inv = rsqrtf(1.0f + 1e-5f);
    #pragma unroll
    for (int rep = 0; rep < 4; rep++) {
        int idx = tid + rep * 256;
        int b = idx >> 7, j = idx & 127;
        float a = fc1b[j];
        #pragma unroll
        for (int k = 0; k < 32; k++) a = fmaf(es[b * 32 + k], fc1w[k * 128 + j], a);
        a = a * (bnfg[j] * inv) + bnfb[j];
        zs[idx] = fmaxf(a, 0.f);
    }
    __syncthreads();
    if (tid < 16) {
        int b = tid >> 1, o = tid & 1;
        float a = fc2b[o];
        for (int k = 0; k < 128; k++) a = fmaf(zs[b * 128 + k], fc2w[k * 2 + o], a);
        dout[b * 2 + o] = a;
    }
}

// ---------------- launch ----------------
extern "C" void kernel_launch(void* const* d_in, const int* in_sizes, int n_in,
                              void* d_out, int out_size, void* d_ws, size_t ws_size,
                              hipStream_t stream) {
    (void)in_sizes; (void)n_in; (void)out_size; (void)ws_size;
    const float* x       = (const float*)d_in[0];
    const float* sinc_w  = (const float*)d_in[1];
    const float* conv1_w = (const float*)d_in[2];
    const float* conv1_b = (const float*)d_in[3];
    const float* bn1_g   = (const float*)d_in[4];
    const float* bn1_b   = (const float*)d_in[5];
    const float* conv2_w = (const float*)d_in[6];
    const float* conv2_b = (const float*)d_in[7];
    const float* bn2_g   = (const float*)d_in[8];
    const float* bn2_b   = (const float*)d_in[9];
    const float* gat1_W  = (const float*)d_in[10];
    const float* gat1_as = (const float*)d_in[11];
    const float* gat1_ad = (const float*)d_in[12];
    const float* gat1_bi = (const float*)d_in[13];
    const float* gat2_W  = (const float*)d_in[14];
    const float* gat2_as = (const float*)d_in[15];
    const float* gat2_ad = (const float*)d_in[16];
    const float* gat2_bi = (const float*)d_in[17];
    const float* fc1_w   = (const float*)d_in[18];
    const float* fc1_b   = (const float*)d_in[19];
    const float* bnf_g   = (const float*)d_in[20];
    const float* bnf_b   = (const float*)d_in[21];
    const float* fc2_w   = (const float*)d_in[22];
    const float* fc2_b   = (const float*)d_in[23];
    float* dout = (float*)d_out;

    float* ws = (float*)d_ws;
    unsigned short* fh  = (unsigned short*)ws;                 // 2048*1024 ush
    unsigned short* fl  = fh + (size_t)MPAD * 1024;
    unsigned short* bch = fl + (size_t)MPAD * 1024;
    unsigned short* bcl = bch + (size_t)NBPAD * 1024;
    unsigned short* bsh = bcl + (size_t)NBPAD * 1024;
    unsigned short* bsl = bsh + (size_t)NBPAD * 1024;
    float* S0   = (float*)(bsl + (size_t)NBPAD * 1024);        // 1,030,104 f
    unsigned short* wbt = (unsigned short*)(S0 + 1030104);     // 32*1056 ush
    float* w1f  = (float*)(wbt + 32 * 1056);
    float* b1f  = w1f + 288;
    float* w2f  = b1f + 32;
    float* b2f  = w2f + 9216;
    unsigned short* bpk = (unsigned short*)(b2f + 32);         // 9,216 ush
    unsigned short* Wt  = (unsigned short*)(b2f + 32 + 4608);  // 512*KPAD ush
    unsigned short* nodesb = Wt + (size_t)512 * KPAD;          // 2000*KPAD ush
    float* h1    = (float*)(nodesb + (size_t)2000 * KPAD);     // 1,024,000
    float* ssrc1 = h1 + 1024000;
    float* sdst1 = ssrc1 + 16000;
    float* smax1 = sdst1 + 16000;
    float* g1    = smax1 + 64;
    float* h2    = g1 + 1024000;
    float* s2src = h2 + 64000;
    float* s2dst = s2src + 2000;
    float* smax2 = s2dst + 2000;
    float* g2    = smax2 + 8;
    float* embp  = g2 + 64000;
    unsigned short* o1g = (unsigned short*)(embp + 256);       // 8*513*251*32 ush
    unsigned short* Pn  = o1g + (size_t)8 * 513 * 251 * 32;    // 64*256*256 ush
    unsigned short* h1t = Pn + (size_t)64 * 256 * 256;         // 64*64*256 ush
    float* hpart = (float*)(h1t + (size_t)64 * 64 * 256);      // 4*1,024,000 f
    unsigned short* P2n = (unsigned short*)(hpart + 4 * 1024000); // 8*256*256 ush
    unsigned short* h2t = P2n + (size_t)8 * 256 * 256;            // 8*32*256 ush

    hipLaunchKernelGGL(k_fold, dim3(38), dim3(256), 0, stream,
                       conv1_w, conv1_b, bn1_g, bn1_b, conv2_w, conv2_b, bn2_g, bn2_b,
                       w1f, b1f, w2f, b2f);
    hipLaunchKernelGGL(k_pack, dim3(36), dim3(256), 0, stream, w2f, bpk);
    hipLaunchKernelGGL(k_wt, dim3(65, 8), dim3(256), 0, stream, gat1_W, Wt);
    hipLaunchKernelGGL(k_wbt, dim3((32 * 1056 + 255) / 256), dim3(256), 0, stream, sinc_w, wbt);
    hipLaunchKernelGGL(k_basis_bf, dim3(NBPAD * 1024 / 256), dim3(256), 0, stream,
                       bch, bcl, bsh, bsl);
    hipLaunchKernelGGL(k_frames_bf, dim3(MPAD * 1024 / 256), dim3(256), 0, stream, x, fh, fl);
    hipLaunchKernelGGL(k_dft_mfma, dim3(9, 64), dim3(256), 0, stream,
                       fh, fl, bch, bcl, bsh, bsl, S0);
    hipLaunchKernelGGL(k_sincm, dim3(4, 8), dim3(256), 0, stream, x, wbt, nodesb);
    hipLaunchKernelGGL(k_conv1, dim3(513, 8), dim3(256), 0, stream, S0, w1f, b1f, o1g);
    hipLaunchKernelGGL(k_conv2m, dim3(8, 32, 8), dim3(256), 0, stream, o1g, bpk, b2f, nodesb);
    hipLaunchKernelGGL(k_gat1s, dim3(8, 32, 4), dim3(256), 0, stream, nodesb, Wt, hpart);
    hipLaunchKernelGGL(k_hred, dim3(4000), dim3(256), 0, stream, hpart, h1, h1t);
    hipLaunchKernelGGL(k_scores1, dim3(500), dim3(256), 0, stream, h1, gat1_as, gat1_ad, ssrc1, sdst1);
    hipLaunchKernelGGL(k_smax1, dim3(64), dim3(64), 0, stream, ssrc1, smax1);
    hipLaunchKernelGGL(k_attw, dim3(64), dim3(256), 0, stream, ssrc1, sdst1, smax1, Pn);
    hipLaunchKernelGGL(k_attnv, dim3(64), dim3(256), 0, stream, Pn, h1t, gat1_bi, g1);
    hipLaunchKernelGGL(k_h2, dim3(500), dim3(256), 0, stream,
                       g1, gat2_W, gat2_as, gat2_ad, h2, h2t, s2src, s2dst);
    hipLaunchKernelGGL(k_smax2, dim3(8), dim3(64), 0, stream, s2src, smax2);
    hipLaunchKernelGGL(k_attw2, dim3(8), dim3(256), 0, stream, s2src, s2dst, smax2, P2n);
    hipLaunchKernelGGL(k_attnv2, dim3(8), dim3(256), 0, stream, P2n, h2t, gat2_bi, g2);
    hipLaunchKernelGGL(k_emb, dim3(8), dim3(256), 0, stream, g2, embp, dout);
    hipLaunchKernelGGL(k_fc, dim3(1), dim3(256), 0, stream,
                       embp, fc1_w, fc1_b, bnf_g, bnf_b, fc2_w, fc2_b, dout);
}

// Round 14
// 378.084 us; speedup vs baseline: 1.0736x; 1.0550x over previous
//
#include <hip/hip_runtime.h>
#include <hip/hip_bf16.h>
#include <math.h>

// ---------------- constants ----------------
#define TB 8
#define TT 64000
#define NFRAMES 251
#define NROWS (TB*NFRAMES)      // 2008
#define GROWS 2048              // 8 * 256 radix-4 sub-rows
#define NBINS 513
#define NBPAD 576
#define NNODE 250
#define NODE_DIM 4116
#define KPAD 4128

typedef __attribute__((ext_vector_type(8))) short short8;
typedef __attribute__((ext_vector_type(4))) float floatx4;

static __device__ __forceinline__ unsigned short f2bf(float x) {
    __hip_bfloat16 h = __float2bfloat16(x);
    return *(unsigned short*)&h;
}
static __device__ __forceinline__ float bf2f(unsigned short u) {
    __hip_bfloat16 h = *(__hip_bfloat16*)&u;
    return __bfloat162float(h);
}

// ---------------- small prep kernels ----------------

__global__ void k_fold(const float* __restrict__ c1w, const float* __restrict__ c1b,
                       const float* __restrict__ g1bn, const float* __restrict__ b1bn,
                       const float* __restrict__ c2w, const float* __restrict__ c2b,
                       const float* __restrict__ g2bn, const float* __restrict__ b2bn,
                       float* __restrict__ w1f, float* __restrict__ b1f,
                       float* __restrict__ w2f, float* __restrict__ b2f) {
    int idx = blockIdx.x * 256 + threadIdx.x;
    float inv = rsqrtf(1.0f + 1e-5f);
    if (idx < 9216) {
        int co = idx / 288;
        w2f[idx] = c2w[idx] * (g2bn[co] * inv);
    } else if (idx < 9216 + 288) {
        int r = idx - 9216;
        w1f[r] = c1w[r] * (g1bn[r / 9] * inv);
    } else if (idx < 9216 + 288 + 32) {
        int c = idx - 9504;
        b1f[c] = c1b[c] * (g1bn[c] * inv) + b1bn[c];
    } else if (idx < 9216 + 288 + 64) {
        int c = idx - 9536;
        b2f[c] = c2b[c] * (g2bn[c] * inv) + b2bn[c];
    }
}

// pack conv2 weights into MFMA B-fragment order, bf16.
__global__ void k_pack(const float* __restrict__ w2f, unsigned short* __restrict__ Bp) {
    int idx = blockIdx.x * 256 + threadIdx.x;
    if (idx >= 9216) return;
    int j = idx & 7, lane = (idx >> 3) & 63, ct = (idx >> 9) & 1, s = idx >> 10;
    int co = ct * 16 + (lane & 15);
    int ci = (lane >> 4) * 8 + j;
    Bp[idx] = f2bf(w2f[co * 288 + ci * 9 + s]);
}

// transpose gat1_W -> Wt [512][KPAD] bf16 with K-permutation
__global__ __launch_bounds__(256) void k_wt(const float* __restrict__ W,
                                            unsigned short* __restrict__ Wt) {
    __shared__ unsigned short tile[64][65];
    int kt = blockIdx.x, nt = blockIdx.y;
    int tid = threadIdx.x;
    for (int idx = tid; idx < 4096; idx += 256) {
        int r = idx >> 6, c = idx & 63;
        int kp = kt * 64 + r;
        int k;
        if (kp < 20) k = kp;
        else if (kp < NODE_DIM) { int t = kp - 20; k = 20 + (t & 15) * 256 + (t >> 4); }
        else k = -1;
        float v = (k >= 0) ? W[k * 512 + nt * 64 + c] : 0.f;
        tile[r][c] = f2bf(v);
    }
    __syncthreads();
    for (int idx = tid; idx < 4096; idx += 256) {
        int nl = idx >> 6, kl = idx & 63;
        int k = kt * 64 + kl;
        if (k < KPAD)
            Wt[(size_t)(nt * 64 + nl) * KPAD + k] = tile[kl][nl];
    }
}

// sinc weights: 4-tap prefix-summed, transposed, padded bf16: wbt[32][1056]
__global__ void k_wbt(const float* __restrict__ sw, unsigned short* __restrict__ wbt) {
    int idx = blockIdx.x * 256 + threadIdx.x;
    if (idx >= 32 * 1056) return;
    int c = idx / 1056, m = idx - c * 1056;
    float s = 0.f;
    if (c < 20 && m < 1027) {
        #pragma unroll
        for (int d = 0; d < 4; d++) {
            int k = m - d;
            if (k >= 0 && k < 1024) s += sw[c * 1024 + k];
        }
        s *= 0.25f;
    }
    wbt[idx] = f2bf(s);
}

// radix-4 DFT basis [NBPAD][256], bf16 hi/lo; rows [NBINS..NBPAD) zero
__global__ void k_basis_bf(unsigned short* __restrict__ ch, unsigned short* __restrict__ cl,
                           unsigned short* __restrict__ sh, unsigned short* __restrict__ sl) {
    int idx = blockIdx.x * 256 + threadIdx.x;
    if (idx >= NBPAD * 256) return;
    int k = idx >> 8, r = idx & 255;
    float s = 0.f, c = 0.f;
    if (k < NBINS) {
        int mm = (k * r) & 1023;
        sincospif((float)mm * (1.0f / 512.0f), &s, &c);
    }
    unsigned short chv = f2bf(c), shv = f2bf(s);
    ch[idx] = chv; cl[idx] = f2bf(c - bf2f(chv));
    sh[idx] = shv; sl[idx] = f2bf(s - bf2f(shv));
}

// radix-4 sub-frames: fh/fl[b*256 + j][r] = xp[b][256j + r] bf16 hi/lo
__global__ void k_frames_bf(const float* __restrict__ x,
                            unsigned short* __restrict__ fh, unsigned short* __restrict__ fl) {
    int idx = blockIdx.x * 256 + threadIdx.x;
    if (idx >= GROWS * 256) return;
    int row = idx >> 8, r = idx & 255;
    int b = row >> 8, j = row & 255;
    int u = j * 256 + r - 512;
    if (u < 0) u = -u;
    if (u >= TT) u = 2 * TT - 2 - u;
    float v = x[b * TT + u];
    unsigned short h = f2bf(v);
    fh[idx] = h;
    fl[idx] = f2bf(v - bf2f(h));
}

// ---------------- sinc conv as MFMA GEMM, M-split ----------------
__global__ __launch_bounds__(256) void k_sincm(const float* __restrict__ x,
                                               const unsigned short* __restrict__ wbt,
                                               unsigned short* __restrict__ nodesb) {
    __shared__ __align__(16) unsigned short xs[1312];
    int ut = blockIdx.x, b = blockIdx.y;
    int tid = threadIdx.x;
    int base = 256 * ut - 512;
    for (int i = tid; i < 1312; i += 256) {
        int g = base + i;
        float v = (g >= 0 && g < TT) ? x[b * TT + g] : 0.f;
        xs[i] = f2bf(v);
    }
    __syncthreads();
    int w = tid >> 6, lane = tid & 63;
    int q = lane >> 4, col = lane & 15;
    floatx4 acc[2];
    acc[0] = acc[1] = (floatx4){0.f, 0.f, 0.f, 0.f};
    for (int K0 = 0; K0 < 1056; K0 += 32) {
        int off = 4 * (w * 16 + col) + K0 + q * 8;
        unsigned long long lo = *(const unsigned long long*)&xs[off];
        unsigned long long hi = *(const unsigned long long*)&xs[off + 4];
        union { unsigned long long u64[2]; short8 s8; } cv;
        cv.u64[0] = lo; cv.u64[1] = hi;
        short8 af = cv.s8;
        #pragma unroll
        for (int ni = 0; ni < 2; ni++) {
            short8 bf = *(const short8*)(wbt + (size_t)(ni * 16 + col) * 1056 + K0 + q * 8);
            acc[ni] = __builtin_amdgcn_mfma_f32_16x16x32_bf16(af, bf, acc[ni], 0, 0, 0);
        }
    }
    #pragma unroll
    for (int ni = 0; ni < 2; ni++)
        #pragma unroll
        for (int rr = 0; rr < 4; rr++) {
            int u = ut * 64 + w * 16 + q * 4 + rr;
            int c = ni * 16 + col;
            if (u < NNODE && c < 20)
                nodesb[(size_t)(b * NNODE + u) * KPAD + c] = f2bf(acc[ni][rr]);
        }
}

// ---------------- radix-4 DFT GEMM: G[row][bin] Re/Im, K=256 ----------------
// grid (9, 64): N0 = bx*64 bins, M0 = by*32 rows.
__global__ __launch_bounds__(256) void k_dft_mfma(const unsigned short* __restrict__ fh,
                                                  const unsigned short* __restrict__ fl,
                                                  const unsigned short* __restrict__ ch,
                                                  const unsigned short* __restrict__ cl,
                                                  const unsigned short* __restrict__ sh,
                                                  const unsigned short* __restrict__ sl,
                                                  float* __restrict__ GRo,
                                                  float* __restrict__ GIo) {
    __shared__ __align__(16) unsigned short Ah[32 * 40];
    __shared__ __align__(16) unsigned short Al[32 * 40];
    __shared__ __align__(16) unsigned short Bch[64 * 40];
    __shared__ __align__(16) unsigned short Bcl[64 * 40];
    __shared__ __align__(16) unsigned short Bsh[64 * 40];
    __shared__ __align__(16) unsigned short Bsl[64 * 40];
    int tid = threadIdx.x;
    int N0 = blockIdx.x * 64, M0 = blockIdx.y * 32;
    int br = tid >> 2, bc = (tid & 3) * 8;
    size_t boff = (size_t)(N0 + br) * 256 + bc;
    int ar = (tid & 127) >> 2, ac = (tid & 3) * 8;
    size_t aoff = (size_t)(M0 + ar) * 256 + ac;
    bool loA = tid < 128;
    int w = tid >> 6, lane = tid & 63;
    int q = lane >> 4, col = lane & 15;
    int mb = (w >> 1) * 16, nb = (w & 1) * 32;
    floatx4 aR[2], aI[2];
    aR[0] = aR[1] = aI[0] = aI[1] = (floatx4){0.f, 0.f, 0.f, 0.f};

    for (int K0 = 0; K0 < 256; K0 += 32) {
        if (loA) *(short8*)&Ah[ar * 40 + ac] = *(const short8*)(fh + aoff + K0);
        else     *(short8*)&Al[ar * 40 + ac] = *(const short8*)(fl + aoff + K0);
        *(short8*)&Bch[br * 40 + bc] = *(const short8*)(ch + boff + K0);
        *(short8*)&Bcl[br * 40 + bc] = *(const short8*)(cl + boff + K0);
        *(short8*)&Bsh[br * 40 + bc] = *(const short8*)(sh + boff + K0);
        *(short8*)&Bsl[br * 40 + bc] = *(const short8*)(sl + boff + K0);
        __syncthreads();
        short8 ahv = *(const short8*)&Ah[(mb + col) * 40 + q * 8];
        short8 alv = *(const short8*)&Al[(mb + col) * 40 + q * 8];
        #pragma unroll
        for (int ni = 0; ni < 2; ni++) {
            short8 chv = *(const short8*)&Bch[(nb + ni * 16 + col) * 40 + q * 8];
            short8 clv = *(const short8*)&Bcl[(nb + ni * 16 + col) * 40 + q * 8];
            short8 shv = *(const short8*)&Bsh[(nb + ni * 16 + col) * 40 + q * 8];
            short8 slv = *(const short8*)&Bsl[(nb + ni * 16 + col) * 40 + q * 8];
            aR[ni] = __builtin_amdgcn_mfma_f32_16x16x32_bf16(ahv, chv, aR[ni], 0, 0, 0);
            aR[ni] = __builtin_amdgcn_mfma_f32_16x16x32_bf16(ahv, clv, aR[ni], 0, 0, 0);
            aR[ni] = __builtin_amdgcn_mfma_f32_16x16x32_bf16(alv, chv, aR[ni], 0, 0, 0);
            aI[ni] = __builtin_amdgcn_mfma_f32_16x16x32_bf16(ahv, shv, aI[ni], 0, 0, 0);
            aI[ni] = __builtin_amdgcn_mfma_f32_16x16x32_bf16(ahv, slv, aI[ni], 0, 0, 0);
            aI[ni] = __builtin_amdgcn_mfma_f32_16x16x32_bf16(alv, shv, aI[ni], 0, 0, 0);
        }
        __syncthreads();
    }
    #pragma unroll
    for (int ni = 0; ni < 2; ni++)
        #pragma unroll
        for (int rr = 0; rr < 4; rr++) {
            int m = M0 + mb + q * 4 + rr;
            int bin = N0 + nb + ni * 16 + col;
            GRo[(size_t)m * NBPAD + bin] = aR[ni][rr];
            GIo[(size_t)m * NBPAD + bin] = aI[ni][rr];
        }
}

// radix-4 combine: F[m,bin] from G[m..m+3,bin] with i^{-bin} twiddles -> S0
__global__ __launch_bounds__(256) void k_dftcomb(const float* __restrict__ GR,
                                                 const float* __restrict__ GI,
                                                 float* __restrict__ S0) {
    int idx = blockIdx.x * 256 + threadIdx.x;
    if (idx >= NROWS * NBINS) return;
    int mg = idx / NBINS, bin = idx - mg * NBINS;
    int b = mg / NFRAMES, i = mg - b * NFRAMES;
    size_t base = ((size_t)(b * 256 + i)) * NBPAD + bin;
    float gr0 = GR[base], gr1 = GR[base + NBPAD], gr2 = GR[base + 2 * NBPAD], gr3 = GR[base + 3 * NBPAD];
    float gs0 = GI[base], gs1 = GI[base + NBPAD], gs2 = GI[base + 2 * NBPAD], gs3 = GI[base + 3 * NBPAD];
    float fre, fim;
    switch (bin & 3) {
        case 0: fre = gr0 + gr1 + gr2 + gr3; fim = gs0 + gs1 + gs2 + gs3; break;
        case 1: fre = gr0 - gs1 - gr2 + gs3; fim = gs0 + gr1 - gs2 - gr3; break;
        case 2: fre = gr0 - gr1 + gr2 - gr3; fim = gs0 - gs1 + gs2 - gs3; break;
        default: fre = gr0 + gs1 - gr2 - gs3; fim = gs0 - gr1 - gs2 + gr3; break;
    }
    S0[(b * NBINS + bin) * NFRAMES + i] = logf(sqrtf(fmaf(fre, fre, fim * fim)) + 1e-9f);
}

// ---------------- conv1+BN+ReLU -> o1g[b][513][251][32] bf16 channels-last ----------------
__global__ __launch_bounds__(256) void k_conv1(const float* __restrict__ S0,
                                               const float* __restrict__ w1f,
                                               const float* __restrict__ b1f,
                                               unsigned short* __restrict__ o1g) {
    __shared__ float w1s[288];
    __shared__ float b1s[32];
    int tid = threadIdx.x;
    for (int i = tid; i < 288; i += 256) w1s[i] = w1f[i];
    if (tid < 32) b1s[tid] = b1f[tid];
    __syncthreads();
    int r = blockIdx.x;
    int b = blockIdx.y;
    int t = tid;
    if (t >= 251) return;
    float sv[9];
    #pragma unroll
    for (int di = 0; di < 3; di++) {
        int rr = r - 1 + di;
        #pragma unroll
        for (int dj = 0; dj < 3; dj++) {
            int tt = t - 1 + dj;
            float v = 0.f;
            if (rr >= 0 && rr < 513 && tt >= 0 && tt < 251)
                v = S0[(b * 513 + rr) * 251 + tt];
            sv[di * 3 + dj] = v;
        }
    }
    unsigned short ov[32];
    #pragma unroll
    for (int ci = 0; ci < 32; ci++) {
        float a = b1s[ci];
        const float* wp = &w1s[ci * 9];
        #pragma unroll
        for (int k = 0; k < 9; k++) a = fmaf(sv[k], wp[k], a);
        ov[ci] = f2bf(fmaxf(a, 0.f));
    }
    unsigned short* dst = o1g + ((size_t)(b * 513 + r) * 251 + t) * 32;
    #pragma unroll
    for (int i = 0; i < 4; i++)
        *(short8*)(dst + i * 8) = *(const short8*)&ov[i * 8];
}

// ---------------- conv2: wide LDS tile, MFMA from LDS, pool, coalesced store ----------------
__global__ __launch_bounds__(256) void k_conv2m(const unsigned short* __restrict__ o1g,
                                                const unsigned short* __restrict__ Bp,
                                                const float* __restrict__ b2f,
                                                unsigned short* __restrict__ nodesb) {
    __shared__ __align__(16) unsigned short o1s[18 * 34 * 32];
    __shared__ float b2s[32];
    int tid = threadIdx.x;
    int b = blockIdx.z;
    int F0 = blockIdx.y * 8;
    int T0 = blockIdx.x * 16;
    if (tid < 32) b2s[tid] = b2f[tid];
    short8 z8 = {0, 0, 0, 0, 0, 0, 0, 0};
    const unsigned short* ob = o1g + (size_t)b * 513 * 251 * 32;

    for (int idx = tid; idx < 2448; idx += 256) {
        int r = idx / 136, rem = idx - r * 136;
        int t = rem >> 2, o = rem & 3;
        int r1 = 2 * F0 - 1 + r, t1 = 2 * T0 - 1 + t;
        short8 v = z8;
        if (r1 >= 0 && r1 < 513 && t1 >= 0 && t1 < 251)
            v = *(const short8*)(ob + ((size_t)r1 * 251 + t1) * 32 + o * 8);
        *(short8*)&o1s[(r * 34 + t) * 32 + o * 8] = v;
    }
    __syncthreads();

    int lane = tid & 63, w = tid >> 6;
    int q = lane >> 4, col = lane & 15;
    floatx4 acc[2][4][2];
    #pragma unroll
    for (int tt = 0; tt < 2; tt++)
        #pragma unroll
        for (int rt = 0; rt < 4; rt++)
            #pragma unroll
            for (int ct = 0; ct < 2; ct++)
                acc[tt][rt][ct] = (floatx4){0.f, 0.f, 0.f, 0.f};

    #pragma unroll
    for (int s = 0; s < 9; s++) {
        const int di = s / 3, dj = s % 3;
        short8 bf0 = *(const short8*)&Bp[(s * 2 + 0) * 512 + lane * 8];
        short8 bf1 = *(const short8*)&Bp[(s * 2 + 1) * 512 + lane * 8];
        #pragma unroll
        for (int tt = 0; tt < 2; tt++)
            #pragma unroll
            for (int rt = 0; rt < 4; rt++) {
                short8 af = *(const short8*)&o1s[((w * 4 + rt + di) * 34 + (col + tt * 16 + dj)) * 32 + q * 8];
                acc[tt][rt][0] = __builtin_amdgcn_mfma_f32_16x16x32_bf16(af, bf0, acc[tt][rt][0], 0, 0, 0);
                acc[tt][rt][1] = __builtin_amdgcn_mfma_f32_16x16x32_bf16(af, bf1, acc[tt][rt][1], 0, 0, 0);
            }
    }
    __syncthreads();

    unsigned short* nb = o1s;
    #pragma unroll
    for (int tt = 0; tt < 2; tt++)
        #pragma unroll
        for (int ct = 0; ct < 2; ct++) {
            float bb = b2s[ct * 16 + col];
            #pragma unroll
            for (int fp2 = 0; fp2 < 2; fp2++)
                #pragma unroll
                for (int tc2 = 0; tc2 < 2; tc2++) {
                    float m0 = fmaxf(
                        fmaxf(acc[tt][2 * fp2][ct][2 * tc2], acc[tt][2 * fp2][ct][2 * tc2 + 1]),
                        fmaxf(acc[tt][2 * fp2 + 1][ct][2 * tc2], acc[tt][2 * fp2 + 1][ct][2 * tc2 + 1]));
                    float v = fmaxf(m0 + bb, 0.f);
                    int nl = (tt * 8 + 2 * q + tc2) * 2 + ct;
                    int fl = 2 * w + fp2;
                    nb[nl * 136 + fl * 16 + col] = f2bf(v);
                }
        }
    __syncthreads();

    int nl = tid >> 3, part = tid & 7;
    int node_g = 2 * T0 + nl;
    if (node_g < NNODE) {
        unsigned short* dst = nodesb + (size_t)(b * NNODE + node_g) * KPAD + 20 + F0 * 16 + part * 16;
        *(short8*)(dst)     = *(const short8*)&nb[nl * 136 + part * 16];
        *(short8*)(dst + 8) = *(const short8*)&nb[nl * 136 + part * 16 + 8];
    }
}

// ---------------- GAT1 GEMM split-K (bf16 MFMA): hpart[kc][2000][512] ----------------
__global__ __launch_bounds__(256) void k_gat1s(const unsigned short* __restrict__ A,
                                               const unsigned short* __restrict__ Bt,
                                               float* __restrict__ hpart) {
    __shared__ __align__(16) unsigned short As[64 * 40];
    __shared__ __align__(16) unsigned short Bs[64 * 40];
    int tid = threadIdx.x;
    int N0 = blockIdx.x * 64, M0 = blockIdx.y * 64;
    int kc = blockIdx.z;
    int ks = (kc == 0) ? 0 : (33 + 32 * (kc - 1));
    int ke = 33 + 32 * kc;
    if (kc == 0) ke = 33;
    int sr = tid >> 2, sc = (tid & 3) * 8;
    int w = tid >> 6, lane = tid & 63;
    int q = lane >> 4, col = lane & 15;
    int mb = (w >> 1) * 32, nb = (w & 1) * 32;
    floatx4 acc[2][2];
    acc[0][0] = acc[0][1] = acc[1][0] = acc[1][1] = (floatx4){0.f, 0.f, 0.f, 0.f};
    short8 z8 = {0, 0, 0, 0, 0, 0, 0, 0};
    int mA = M0 + sr;
    bool mv = mA < 2000;
    const unsigned short* pa = A + (size_t)mA * KPAD + sc;
    const unsigned short* pb = Bt + (size_t)(N0 + sr) * KPAD + sc;

    for (int kk = ks; kk < ke; kk++) {
        int K0 = kk * 32;
        short8 va = mv ? *(const short8*)(pa + K0) : z8;
        short8 vb = *(const short8*)(pb + K0);
        *(short8*)&As[sr * 40 + sc] = va;
        *(short8*)&Bs[sr * 40 + sc] = vb;
        __syncthreads();
        short8 a0 = *(const short8*)&As[(mb + col) * 40 + q * 8];
        short8 a1 = *(const short8*)&As[(mb + 16 + col) * 40 + q * 8];
        short8 b0 = *(const short8*)&Bs[(nb + col) * 40 + q * 8];
        short8 b1 = *(const short8*)&Bs[(nb + 16 + col) * 40 + q * 8];
        acc[0][0] = __builtin_amdgcn_mfma_f32_16x16x32_bf16(a0, b0, acc[0][0], 0, 0, 0);
        acc[0][1] = __builtin_amdgcn_mfma_f32_16x16x32_bf16(a0, b1, acc[0][1], 0, 0, 0);
        acc[1][0] = __builtin_amdgcn_mfma_f32_16x16x32_bf16(a1, b0, acc[1][0], 0, 0, 0);
        acc[1][1] = __builtin_amdgcn_mfma_f32_16x16x32_bf16(a1, b1, acc[1][1], 0, 0, 0);
        __syncthreads();
    }
    float* out = hpart + (size_t)kc * 1024000;
    #pragma unroll
    for (int mi = 0; mi < 2; mi++)
        #pragma unroll
        for (int ni = 0; ni < 2; ni++)
            #pragma unroll
            for (int rr = 0; rr < 4; rr++) {
                int m = M0 + mb + mi * 16 + q * 4 + rr;
                if (m < 2000)
                    out[m * 512 + N0 + nb + ni * 16 + col] = acc[mi][ni][rr];
            }
}

// reduce 4 partials -> h1 f32 + h1t bf16 [bh][f][256]
__global__ __launch_bounds__(256) void k_hred(const float* __restrict__ hpart,
                                              float* __restrict__ h1,
                                              unsigned short* __restrict__ h1t) {
    int idx = blockIdx.x * 256 + threadIdx.x;
    if (idx >= 1024000) return;
    float s = hpart[idx] + hpart[idx + 1024000] + hpart[idx + 2048000] + hpart[idx + 3072000];
    h1[idx] = s;
    int m = idx >> 9, n = idx & 511;
    int bb = m / NNODE, j = m - bb * NNODE;
    int hh = n >> 6, f = n & 63;
    h1t[((size_t)((bb * 8 + hh) * 64 + f)) * 256 + j] = f2bf(s);
}

// ---------------- GAT1 scores / max ----------------
__global__ __launch_bounds__(256) void k_scores1(const float* __restrict__ h1,
                                                 const float* __restrict__ asrc,
                                                 const float* __restrict__ adst,
                                                 float* __restrict__ ssrc,
                                                 float* __restrict__ sdst) {
    int row = blockIdx.x * 4 + (threadIdx.x >> 6);
    int lane = threadIdx.x & 63;
    if (row >= 2000) return;
    for (int h = 0; h < 8; h++) {
        float v = h1[row * 512 + h * 64 + lane];
        float ps = v * asrc[h * 64 + lane];
        float pd = v * adst[h * 64 + lane];
        for (int off = 32; off > 0; off >>= 1) {
            ps += __shfl_down(ps, off);
            pd += __shfl_down(pd, off);
        }
        if (lane == 0) { ssrc[row * 8 + h] = ps; sdst[row * 8 + h] = pd; }
    }
}

__global__ __launch_bounds__(64) void k_smax1(const float* __restrict__ ssrc,
                                              float* __restrict__ smax) {
    int bh = blockIdx.x;
    int b = bh >> 3, h = bh & 7;
    int lane = threadIdx.x;
    float m = -1e30f;
    for (int n = lane; n < NNODE; n += 64) m = fmaxf(m, ssrc[(b * NNODE + n) * 8 + h]);
    for (int off = 32; off > 0; off >>= 1) m = fmaxf(m, __shfl_down(m, off));
    if (lane == 0) smax[bh] = m;
}

// ---------------- GAT1 attention weights: Pn[bh][256][256] bf16 normalized ----------------
__global__ __launch_bounds__(256) void k_attw(const float* __restrict__ ssrc,
                                              const float* __restrict__ sdst,
                                              const float* __restrict__ smax,
                                              unsigned short* __restrict__ Pn) {
    int bh = blockIdx.x;
    int b = bh >> 3, h = bh & 7;
    int tid = threadIdx.x;
    __shared__ float ss[NNODE];
    for (int j = tid; j < NNODE; j += 256) ss[j] = ssrc[(b * NNODE + j) * 8 + h];
    __syncthreads();
    unsigned short* row = Pn + ((size_t)bh * 256 + tid) * 256;
    short8 z8 = {0, 0, 0, 0, 0, 0, 0, 0};
    if (tid >= NNODE) {
        #pragma unroll
        for (int j = 0; j < 256; j += 8) *(short8*)(row + j) = z8;
        return;
    }
    float d = sdst[(b * NNODE + tid) * 8 + h];
    float e0 = d + smax[bh];
    float mx = e0 > 0.f ? e0 : 0.2f * e0;
    float den = 0.f;
    for (int j = 0; j < NNODE; j++) {
        float e = d + ss[j];
        e = e > 0.f ? e : 0.2f * e;
        den += __expf(e - mx);
    }
    float rden = 1.f / den;
    for (int j0 = 0; j0 < 256; j0 += 8) {
        unsigned short wv[8];
        #pragma unroll
        for (int jj = 0; jj < 8; jj++) {
            int j = j0 + jj;
            float wt = 0.f;
            if (j < NNODE) {
                float e = d + ss[j];
                e = e > 0.f ? e : 0.2f * e;
                wt = __expf(e - mx) * rden;
            }
            wv[jj] = f2bf(wt);
        }
        *(short8*)(row + j0) = *(const short8*)wv;
    }
}

// ---------------- GAT1 attention apply (MFMA): g1 = Pn @ h1t^T + bias, relu ----------------
__global__ __launch_bounds__(256) void k_attnv(const unsigned short* __restrict__ Pn,
                                               const unsigned short* __restrict__ h1t,
                                               const float* __restrict__ bias,
                                               float* __restrict__ g1) {
    int bh = blockIdx.x;
    int b = bh >> 3, h = bh & 7;
    int tid = threadIdx.x;
    int w = tid >> 6, lane = tid & 63;
    int q = lane >> 4, col = lane & 15;
    const unsigned short* Pb = Pn + (size_t)bh * 65536;
    const unsigned short* Hb = h1t + (size_t)bh * 16384;
    floatx4 acc[4][4];
    #pragma unroll
    for (int mi = 0; mi < 4; mi++)
        #pragma unroll
        for (int ni = 0; ni < 4; ni++)
            acc[mi][ni] = (floatx4){0.f, 0.f, 0.f, 0.f};
    for (int k0 = 0; k0 < 256; k0 += 32) {
        short8 af[4], bf[4];
        #pragma unroll
        for (int mi = 0; mi < 4; mi++)
            af[mi] = *(const short8*)(Pb + (size_t)((w * 4 + mi) * 16 + col) * 256 + k0 + q * 8);
        #pragma unroll
        for (int ni = 0; ni < 4; ni++)
            bf[ni] = *(const short8*)(Hb + (size_t)(ni * 16 + col) * 256 + k0 + q * 8);
        #pragma unroll
        for (int mi = 0; mi < 4; mi++)
            #pragma unroll
            for (int ni = 0; ni < 4; ni++)
                acc[mi][ni] = __builtin_amdgcn_mfma_f32_16x16x32_bf16(af[mi], bf[ni], acc[mi][ni], 0, 0, 0);
    }
    #pragma unroll
    for (int mi = 0; mi < 4; mi++)
        #pragma unroll
        for (int ni = 0; ni < 4; ni++)
            #pragma unroll
            for (int rr = 0; rr < 4; rr++) {
                int i = (w * 4 + mi) * 16 + q * 4 + rr;
                int f = ni * 16 + col;
                if (i < NNODE)
                    g1[(b * NNODE + i) * 512 + h * 64 + f] =
                        fmaxf(acc[mi][ni][rr] + bias[h * 64 + f], 0.f);
            }
}

// ---------------- GAT2 ----------------
__global__ __launch_bounds__(256) void k_h2(const float* __restrict__ g1,
                                            const float* __restrict__ W2,
                                            const float* __restrict__ a2src,
                                            const float* __restrict__ a2dst,
                                            float* __restrict__ h2,
                                            unsigned short* __restrict__ h2t,
                                            float* __restrict__ s2src,
                                            float* __restrict__ s2dst) {
    int row = blockIdx.x * 4 + (threadIdx.x >> 6);
    if (row >= 2000) return;
    int lane = threadIdx.x & 63;
    int o = lane & 31, half = lane >> 5;
    const float* gr = &g1[row * 512 + half * 256];
    float acc = 0.f;
    for (int k = 0; k < 256; k++) acc = fmaf(gr[k], W2[(half * 256 + k) * 32 + o], acc);
    acc += __shfl_down(acc, 32);
    float ps = acc * a2src[o], pd = acc * a2dst[o];
    for (int off = 16; off > 0; off >>= 1) {
        ps += __shfl_down(ps, off, 32);
        pd += __shfl_down(pd, off, 32);
    }
    if (lane == 0) { s2src[row] = ps; s2dst[row] = pd; }
    if (lane < 32) {
        h2[row * 32 + o] = acc;
        int b = row / NNODE, j = row - b * NNODE;
        h2t[((size_t)(b * 32 + o)) * 256 + j] = f2bf(acc);
    }
}

__global__ __launch_bounds__(64) void k_smax2(const float* __restrict__ s2src,
                                              float* __restrict__ smax2) {
    int b = blockIdx.x, lane = threadIdx.x;
    float m = -1e30f;
    for (int n = lane; n < NNODE; n += 64) m = fmaxf(m, s2src[b * NNODE + n]);
    for (int off = 32; off > 0; off >>= 1) m = fmaxf(m, __shfl_down(m, off));
    if (lane == 0) smax2[b] = m;
}

// GAT2 attention weights: P2n[b][256][256] bf16 normalized
__global__ __launch_bounds__(256) void k_attw2(const float* __restrict__ s2src,
                                               const float* __restrict__ s2dst,
                                               const float* __restrict__ smax2,
                                               unsigned short* __restrict__ P2n) {
    int b = blockIdx.x;
    int tid = threadIdx.x;
    __shared__ float ss[NNODE];
    for (int j = tid; j < NNODE; j += 256) ss[j] = s2src[b * NNODE + j];
    __syncthreads();
    unsigned short* row = P2n + ((size_t)b * 256 + tid) * 256;
    short8 z8 = {0, 0, 0, 0, 0, 0, 0, 0};
    if (tid >= NNODE) {
        #pragma unroll
        for (int j = 0; j < 256; j += 8) *(short8*)(row + j) = z8;
        return;
    }
    float d = s2dst[b * NNODE + tid];
    float e0 = d + smax2[b];
    float mx = e0 > 0.f ? e0 : 0.2f * e0;
    float den = 0.f;
    for (int j = 0; j < NNODE; j++) {
        float e = d + ss[j];
        e = e > 0.f ? e : 0.2f * e;
        den += __expf(e - mx);
    }
    float rden = 1.f / den;
    for (int j0 = 0; j0 < 256; j0 += 8) {
        unsigned short wv[8];
        #pragma unroll
        for (int jj = 0; jj < 8; jj++) {
            int j = j0 + jj;
            float wt = 0.f;
            if (j < NNODE) {
                float e = d + ss[j];
                e = e > 0.f ? e : 0.2f * e;
                wt = __expf(e - mx) * rden;
            }
            wv[jj] = f2bf(wt);
        }
        *(short8*)(row + j0) = *(const short8*)wv;
    }
}

// GAT2 attention apply (MFMA): g2 = P2n @ h2t^T + bias2
__global__ __launch_bounds__(256) void k_attnv2(const unsigned short* __restrict__ P2n,
                                                const unsigned short* __restrict__ h2t,
                                                const float* __restrict__ bias2,
                                                float* __restrict__ g2) {
    int b = blockIdx.x;
    int tid = threadIdx.x;
    int w = tid >> 6, lane = tid & 63;
    int q = lane >> 4, col = lane & 15;
    const unsigned short* Pb = P2n + (size_t)b * 65536;
    const unsigned short* Hb = h2t + (size_t)b * 8192;
    floatx4 acc[4][2];
    #pragma unroll
    for (int mi = 0; mi < 4; mi++)
        #pragma unroll
        for (int ni = 0; ni < 2; ni++)
            acc[mi][ni] = (floatx4){0.f, 0.f, 0.f, 0.f};
    for (int k0 = 0; k0 < 256; k0 += 32) {
        short8 af[4], bf[2];
        #pragma unroll
        for (int mi = 0; mi < 4; mi++)
            af[mi] = *(const short8*)(Pb + (size_t)((w * 4 + mi) * 16 + col) * 256 + k0 + q * 8);
        #pragma unroll
        for (int ni = 0; ni < 2; ni++)
            bf[ni] = *(const short8*)(Hb + (size_t)(ni * 16 + col) * 256 + k0 + q * 8);
        #pragma unroll
        for (int mi = 0; mi < 4; mi++)
            #pragma unroll
            for (int ni = 0; ni < 2; ni++)
                acc[mi][ni] = __builtin_amdgcn_mfma_f32_16x16x32_bf16(af[mi], bf[ni], acc[mi][ni], 0, 0, 0);
    }
    #pragma unroll
    for (int mi = 0; mi < 4; mi++)
        #pragma unroll
        for (int ni = 0; ni < 2; ni++)
            #pragma unroll
            for (int rr = 0; rr < 4; rr++) {
                int i = (w * 4 + mi) * 16 + q * 4 + rr;
                int f = ni * 16 + col;
                if (i < NNODE)
                    g2[(b * NNODE + i) * 32 + f] = acc[mi][ni][rr] + bias2[f];
            }
}

__global__ __launch_bounds__(256) void k_emb(const float* __restrict__ g2,
                                             float* __restrict__ emb,
                                             float* __restrict__ dout) {
    int b = blockIdx.x;
    int f = threadIdx.x & 31, g = threadIdx.x >> 5;
    __shared__ float red[8][32];
    float s = 0.f;
    for (int i = g; i < NNODE; i += 8) s += g2[(b * NNODE + i) * 32 + f];
    red[g][f] = s;
    __syncthreads();
    if (threadIdx.x < 32) {
        float t = 0.f;
        #pragma unroll
        for (int gg = 0; gg < 8; gg++) t += red[gg][f];
        t *= (1.0f / 250.0f);
        emb[b * 32 + f] = t;
        dout[16 + b * 32 + f] = t;
    }
}

__global__ __launch_bounds__(256) void k_fc(const float* __restrict__ emb,
                                            const float* __restrict__ fc1w,
                                            const float* __restrict__ fc1b,
                                            const float* __restrict__ bnfg,
                                            const float* __restrict__ bnfb,
                                            const float* __restrict__ fc2w,
                                            const float* __restrict__ fc2b,
                                            float* __restrict__ dout) {
    __shared__ float es[256];
    __shared__ float zs[1024];
    int tid = threadIdx.x;
    es[tid] = emb[tid];
    __syncthreads();
    float inv = rsqrtf(1.0f + 1e-5f);
    #pragma unroll
    for (int rep = 0; rep < 4; rep++) {
        int idx = tid + rep * 256;
        int b = idx >> 7, j = idx & 127;
        float a = fc1b[j];
        #pragma unroll
        for (int k = 0; k < 32; k++) a = fmaf(es[b * 32 + k], fc1w[k * 128 + j], a);
        a = a * (bnfg[j] * inv) + bnfb[j];
        zs[idx] = fmaxf(a, 0.f);
    }
    __syncthreads();
    if (tid < 16) {
        int b = tid >> 1, o = tid & 1;
        float a = fc2b[o];
        for (int k = 0; k < 128; k++) a = fmaf(zs[b * 128 + k], fc2w[k * 2 + o], a);
        dout[b * 2 + o] = a;
    }
}

// ---------------- launch ----------------
extern "C" void kernel_launch(void* const* d_in, const int* in_sizes, int n_in,
                              void* d_out, int out_size, void* d_ws, size_t ws_size,
                              hipStream_t stream) {
    (void)in_sizes; (void)n_in; (void)out_size; (void)ws_size;
    const float* x       = (const float*)d_in[0];
    const float* sinc_w  = (const float*)d_in[1];
    const float* conv1_w = (const float*)d_in[2];
    const float* conv1_b = (const float*)d_in[3];
    const float* bn1_g   = (const float*)d_in[4];
    const float* bn1_b   = (const float*)d_in[5];
    const float* conv2_w = (const float*)d_in[6];
    const float* conv2_b = (const float*)d_in[7];
    const float* bn2_g   = (const float*)d_in[8];
    const float* bn2_b   = (const float*)d_in[9];
    const float* gat1_W  = (const float*)d_in[10];
    const float* gat1_as = (const float*)d_in[11];
    const float* gat1_ad = (const float*)d_in[12];
    const float* gat1_bi = (const float*)d_in[13];
    const float* gat2_W  = (const float*)d_in[14];
    const float* gat2_as = (const float*)d_in[15];
    const float* gat2_ad = (const float*)d_in[16];
    const float* gat2_bi = (const float*)d_in[17];
    const float* fc1_w   = (const float*)d_in[18];
    const float* fc1_b   = (const float*)d_in[19];
    const float* bnf_g   = (const float*)d_in[20];
    const float* bnf_b   = (const float*)d_in[21];
    const float* fc2_w   = (const float*)d_in[22];
    const float* fc2_b   = (const float*)d_in[23];
    float* dout = (float*)d_out;

    float* ws = (float*)d_ws;
    unsigned short* fh  = (unsigned short*)ws;                 // 2048*256 ush
    unsigned short* fl  = fh + (size_t)GROWS * 256;
    unsigned short* bch = fl + (size_t)GROWS * 256;            // 576*256 ush x4
    unsigned short* bcl = bch + (size_t)NBPAD * 256;
    unsigned short* bsh = bcl + (size_t)NBPAD * 256;
    unsigned short* bsl = bsh + (size_t)NBPAD * 256;
    float* GRb  = (float*)(bsl + (size_t)NBPAD * 256);         // 2048*576 f
    float* GIb  = GRb + (size_t)GROWS * NBPAD;                 // 2048*576 f
    float* S0   = GIb + (size_t)GROWS * NBPAD;                 // 1,030,104 f
    unsigned short* wbt = (unsigned short*)(S0 + 1030104);     // 32*1056 ush
    float* w1f  = (float*)(wbt + 32 * 1056);
    float* b1f  = w1f + 288;
    float* w2f  = b1f + 32;
    float* b2f  = w2f + 9216;
    unsigned short* bpk = (unsigned short*)(b2f + 32);         // 9,216 ush
    unsigned short* Wt  = (unsigned short*)(b2f + 32 + 4608);  // 512*KPAD ush
    unsigned short* nodesb = Wt + (size_t)512 * KPAD;          // 2000*KPAD ush
    float* h1    = (float*)(nodesb + (size_t)2000 * KPAD);     // 1,024,000
    float* ssrc1 = h1 + 1024000;
    float* sdst1 = ssrc1 + 16000;
    float* smax1 = sdst1 + 16000;
    float* g1    = smax1 + 64;
    float* h2    = g1 + 1024000;
    float* s2src = h2 + 64000;
    float* s2dst = s2src + 2000;
    float* smax2 = s2dst + 2000;
    float* g2    = smax2 + 8;
    float* embp  = g2 + 64000;
    unsigned short* o1g = (unsigned short*)(embp + 256);       // 8*513*251*32 ush
    unsigned short* Pn  = o1g + (size_t)8 * 513 * 251 * 32;    // 64*256*256 ush
    unsigned short* h1t = Pn + (size_t)64 * 256 * 256;         // 64*64*256 ush
    float* hpart = (float*)(h1t + (size_t)64 * 64 * 256);      // 4*1,024,000 f
    unsigned short* P2n = (unsigned short*)(hpart + 4 * 1024000); // 8*256*256 ush
    unsigned short* h2t = P2n + (size_t)8 * 256 * 256;            // 8*32*256 ush

    hipLaunchKernelGGL(k_fold, dim3(38), dim3(256), 0, stream,
                       conv1_w, conv1_b, bn1_g, bn1_b, conv2_w, conv2_b, bn2_g, bn2_b,
                       w1f, b1f, w2f, b2f);
    hipLaunchKernelGGL(k_pack, dim3(36), dim3(256), 0, stream, w2f, bpk);
    hipLaunchKernelGGL(k_wt, dim3(65, 8), dim3(256), 0, stream, gat1_W, Wt);
    hipLaunchKernelGGL(k_wbt, dim3((32 * 1056 + 255) / 256), dim3(256), 0, stream, sinc_w, wbt);
    hipLaunchKernelGGL(k_basis_bf, dim3(NBPAD), dim3(256), 0, stream,
                       bch, bcl, bsh, bsl);
    hipLaunchKernelGGL(k_frames_bf, dim3(GROWS), dim3(256), 0, stream, x, fh, fl);
    hipLaunchKernelGGL(k_dft_mfma, dim3(9, 64), dim3(256), 0, stream,
                       fh, fl, bch, bcl, bsh, bsl, GRb, GIb);
    hipLaunchKernelGGL(k_dftcomb, dim3((NROWS * NBINS + 255) / 256), dim3(256), 0, stream,
                       GRb, GIb, S0);
    hipLaunchKernelGGL(k_sincm, dim3(4, 8), dim3(256), 0, stream, x, wbt, nodesb);
    hipLaunchKernelGGL(k_conv1, dim3(513, 8), dim3(256), 0, stream, S0, w1f, b1f, o1g);
    hipLaunchKernelGGL(k_conv2m, dim3(8, 32, 8), dim3(256), 0, stream, o1g, bpk, b2f, nodesb);
    hipLaunchKernelGGL(k_gat1s, dim3(8, 32, 4), dim3(256), 0, stream, nodesb, Wt, hpart);
    hipLaunchKernelGGL(k_hred, dim3(4000), dim3(256), 0, stream, hpart, h1, h1t);
    hipLaunchKernelGGL(k_scores1, dim3(500), dim3(256), 0, stream, h1, gat1_as, gat1_ad, ssrc1, sdst1);
    hipLaunchKernelGGL(k_smax1, dim3(64), dim3(64), 0, stream, ssrc1, smax1);
    hipLaunchKernelGGL(k_attw, dim3(64), dim3(256), 0, stream, ssrc1, sdst1, smax1, Pn);
    hipLaunchKernelGGL(k_attnv, dim3(64), dim3(256), 0, stream, Pn, h1t, gat1_bi, g1);
    hipLaunchKernelGGL(k_h2, dim3(500), dim3(256), 0, stream,
                       g1, gat2_W, gat2_as, gat2_ad, h2, h2t, s2src, s2dst);
    hipLaunchKernelGGL(k_smax2, dim3(8), dim3(64), 0, stream, s2src, smax2);
    hipLaunchKernelGGL(k_attw2, dim3(8), dim3(256), 0, stream, s2src, s2dst, smax2, P2n);
    hipLaunchKernelGGL(k_attnv2, dim3(8), dim3(256), 0, stream, P2n, h2t, gat2_bi, g2);
    hipLaunchKernelGGL(k_emb, dim3(8), dim3(256), 0, stream, g2, embp, dout);
    hipLaunchKernelGGL(k_fc, dim3(1), dim3(256), 0, stream,
                       embp, fc1_w, fc1_b, bnf_g, bnf_b, fc2_w, fc2_b, dout);
}